// Round 11
// baseline (176.124 us; speedup 1.0000x reference)
//
#include <hip/hip_runtime.h>
#include <math.h>

#define T_SEQ 4096
#define ROWS 8192
#define NCHUNK 128
#define CLEN 32

typedef __attribute__((ext_vector_type(4))) float f32x4;
typedef __attribute__((ext_vector_type(2))) float f32x2;
typedef __attribute__((ext_vector_type(8))) short s16x8;

#if __has_builtin(__builtin_elementwise_fma)
#define PKFMA(a, b, c) __builtin_elementwise_fma((a), (b), (c))
#else
#define PKFMA(a, b, c) ((a) * (b) + (c))
#endif

__device__ __forceinline__ float siluf(float x) { return x / (1.f + __expf(-x)); }
__device__ __forceinline__ float softplusf(float x) {
    return fmaxf(x, 0.f) + __logf(1.f + __expf(-fabsf(x)));
}
__device__ __forceinline__ ushort f2b(float f) {
    uint u = __float_as_uint(f);
    u += 0x7fffu + ((u >> 16) & 1u);
    return (ushort)(u >> 16);
}
__device__ __forceinline__ float b2f(ushort h) { return __uint_as_float(((uint)h) << 16); }

// direct global->LDS, 16B per lane.
__device__ __forceinline__ void gl16(const ushort* g, const char* l)
{
    __builtin_amdgcn_global_load_lds(
        (const __attribute__((address_space(1))) void*)g,
        (__attribute__((address_space(3))) void*)l,
        16, 0, 0);
}

// ---------------------------------------------------------------------------
// Merged prep kernel (one launch):
//  blocks 0..1023    : x fp32 -> bf16 (xbh)
//  1024..1151        : transpose fW_in -> WinT_f [1024][256]
//  1152..1279        : transpose bW_in -> WinT_b
//  1280..1791        : fusewT fw -> WallOut[:, 0:512)
//  1792..2303        : fusewT bw -> WallOut[:, 512:1024)
//  2304..2463        : wallT fw -> Wall_f [640][512]
//  2464..2623        : wallT bw -> Wall_b
// ---------------------------------------------------------------------------
__device__ __forceinline__ void cvt_body(const float* in, ushort* out, int bid, int tid)
{
    int i = bid * 256 + tid;
    const float4* p = reinterpret_cast<const float4*>(in) + (size_t)i * 2;
    float4 a = p[0], b = p[1];
    s16x8 v;
    v[0] = (short)f2b(a.x); v[1] = (short)f2b(a.y); v[2] = (short)f2b(a.z); v[3] = (short)f2b(a.w);
    v[4] = (short)f2b(b.x); v[5] = (short)f2b(b.y); v[6] = (short)f2b(b.z); v[7] = (short)f2b(b.w);
    *reinterpret_cast<s16x8*>(out + (size_t)i * 8) = v;
}

__device__ __forceinline__ void transpose_body(const float* W, ushort* WT,
                                               int Kdim, int Ndim, int bid, int tid)
{
    int idx = bid * 256 + tid;
    int kg8 = Kdim >> 3;
    if (idx >= Ndim * kg8) return;
    int n = idx / kg8, kg = idx - n * kg8;
    s16x8 v;
    #pragma unroll
    for (int i = 0; i < 8; ++i)
        v[i] = (short)f2b(W[(size_t)(kg * 8 + i) * Ndim + n]);
    *reinterpret_cast<s16x8*>(WT + (size_t)n * Kdim + kg * 8) = v;
}

__device__ __forceinline__ void fusew_body(const float* W_out, const float* merge,
                                           ushort* WT, int mrow0, int koff, int bid, int tid)
{
    int idx = bid * 256 + tid;   // dd*256 + j
    int dd = idx >> 8, j = idx & 255;
    float acc = 0.f;
    const float* wr = W_out + dd * 256;
    const float* mc = merge + (size_t)mrow0 * 256 + j;
    #pragma unroll 4
    for (int m = 0; m < 256; ++m)
        acc = fmaf(wr[m], mc[(size_t)m * 256], acc);
    WT[(size_t)j * 1024 + koff + dd] = f2b(acc);
}

__device__ __forceinline__ void wall_body(const float* Wx, const float* Wdt,
                                          ushort* WT, int bid, int tid)
{
    int idx = bid * 256 + tid;   // n*64 + kg
    int n = idx >> 6, kg = idx & 63;
    s16x8 v;
    #pragma unroll
    for (int i = 0; i < 8; ++i) {
        int k = kg * 8 + i;
        float acc = 0.f;
        if (n < 512) {
            #pragma unroll
            for (int j = 0; j < 16; ++j)
                acc = fmaf(Wx[k * 48 + j], Wdt[j * 512 + n], acc);
        } else if (n < 544) {
            acc = Wx[k * 48 + 16 + (n - 512)];
        }
        v[i] = (short)f2b(acc);
    }
    *reinterpret_cast<s16x8*>(WT + (size_t)n * 512 + kg * 8) = v;
}

__global__ __launch_bounds__(256)
void prep_kernel(const float* __restrict__ x,
                 const float* __restrict__ fW_in, const float* __restrict__ bW_in,
                 const float* __restrict__ fW_out, const float* __restrict__ bW_out,
                 const float* __restrict__ merge,
                 const float* __restrict__ fW_x, const float* __restrict__ fW_dt,
                 const float* __restrict__ bW_x, const float* __restrict__ bW_dt,
                 ushort* __restrict__ xbh,
                 ushort* __restrict__ WinT_f, ushort* __restrict__ WinT_b,
                 ushort* __restrict__ WallOut,
                 ushort* __restrict__ Wall_f, ushort* __restrict__ Wall_b)
{
    int bid = blockIdx.x, tid = threadIdx.x;
    if (bid < 1024)        cvt_body(x, xbh, bid, tid);
    else if (bid < 1152)   transpose_body(fW_in, WinT_f, 256, 1024, bid - 1024, tid);
    else if (bid < 1280)   transpose_body(bW_in, WinT_b, 256, 1024, bid - 1152, tid);
    else if (bid < 1792)   fusew_body(fW_out, merge, WallOut, 0, 0, bid - 1280, tid);
    else if (bid < 2304)   fusew_body(bW_out, merge, WallOut, 256, 512, bid - 1792, tid);
    else if (bid < 2464)   wall_body(fW_x, fW_dt, Wall_f, bid - 2304, tid);
    else                   wall_body(bW_x, bW_dt, Wall_b, bid - 2464, tid);
}

// ---------------------------------------------------------------------------
// bf16 MFMA GEMM, m97 structure (unchanged).
// ---------------------------------------------------------------------------
template<int BM, int BN, int EPI>
__global__ __launch_bounds__(256)
void mgemm(const ushort* __restrict__ A0, const ushort* __restrict__ A1,
           const ushort* __restrict__ B0, const ushort* __restrict__ B1,
           void* __restrict__ C0, void* __restrict__ C1,
           const float* __restrict__ bias0, const float* __restrict__ bias1,
           float* __restrict__ X0, float* __restrict__ X1,
           int K, int ldc, int flip0, int flip1, int zmode, int nseg)
{
    constexpr int MF = BM / 32, NF = BN / 32;
    constexpr int ASTR = BM / 32, BSTR = BN / 32;
    constexpr int ABYTES = BM * 128;
    __shared__ char lds[BM * 128 + BN * 128];

    const int tid = threadIdx.x;
    const int L = tid & 63, w = tid >> 6;
    const int wm = w >> 1, wn = w & 1;
    const int m0 = blockIdx.y * BM, n0 = blockIdx.x * BN;

    f32x4 acc[MF][NF];
    #pragma unroll
    for (int i = 0; i < MF; ++i)
        #pragma unroll
        for (int j = 0; j < NF; ++j)
            acc[i][j] = (f32x4){0.f, 0.f, 0.f, 0.f};

    const int rsub = L >> 3;
    const int q = (L & 7) ^ rsub;
    const int sb = zmode ? blockIdx.z : 0;
    const int se = zmode ? sb + 1 : nseg;

    for (int s = sb; s < se; ++s) {
        const ushort* Ap = s ? A1 : A0;
        const ushort* Bp = s ? B1 : B0;
        const int flip = s ? flip1 : flip0;

        const ushort* ap[ASTR];
        const ushort* bp[BSTR];
        #pragma unroll
        for (int c = 0; c < ASTR; ++c) {
            int rg = m0 + (w * ASTR + c) * 8 + rsub;
            if (flip) rg ^= (T_SEQ - 1);
            ap[c] = Ap + (size_t)rg * K + q * 8;
        }
        #pragma unroll
        for (int c = 0; c < BSTR; ++c) {
            int ng = n0 + (w * BSTR + c) * 8 + rsub;
            bp[c] = Bp + (size_t)ng * K + q * 8;
        }

        for (int k0 = 0; k0 < K; k0 += 64) {
            #pragma unroll
            for (int c = 0; c < ASTR; ++c) {
                gl16(ap[c], lds + (w * ASTR + c) * 1024);
                ap[c] += 64;
            }
            #pragma unroll
            for (int c = 0; c < BSTR; ++c) {
                gl16(bp[c], lds + ABYTES + (w * BSTR + c) * 1024);
                bp[c] += 64;
            }
            __syncthreads();
            #pragma unroll
            for (int kk = 0; kk < 2; ++kk) {
                const int sw = (((kk * 4 + (L >> 4)) ^ (L & 7)) << 4);
                s16x8 af[MF], bf[NF];
                #pragma unroll
                for (int i = 0; i < MF; ++i) {
                    int R = wm * (BM / 2) + i * 16 + (L & 15);
                    af[i] = *reinterpret_cast<const s16x8*>(lds + R * 128 + sw);
                }
                #pragma unroll
                for (int j = 0; j < NF; ++j) {
                    int R = wn * (BN / 2) + j * 16 + (L & 15);
                    bf[j] = *reinterpret_cast<const s16x8*>(lds + ABYTES + R * 128 + sw);
                }
                #pragma unroll
                for (int i = 0; i < MF; ++i)
                    #pragma unroll
                    for (int j = 0; j < NF; ++j)
                        acc[i][j] = __builtin_amdgcn_mfma_f32_16x16x32_bf16(
                            af[i], bf[j], acc[i][j], 0, 0, 0);
            }
            __syncthreads();
        }
    }

    void* Cv = (zmode && blockIdx.z) ? C1 : C0;
    const float* bias = (zmode && blockIdx.z) ? bias1 : bias0;
    float* Xv = (zmode && blockIdx.z) ? X1 : X0;
    #pragma unroll
    for (int i = 0; i < MF; ++i) {
        #pragma unroll
        for (int j = 0; j < NF; ++j) {
            int r0 = m0 + wm * (BM / 2) + i * 16 + ((L >> 4) << 2);
            int c  = n0 + wn * (BN / 2) + j * 16 + (L & 15);
            if (EPI == 2) {
                if (c < 512) {
                    float bv = bias[c];
                    #pragma unroll
                    for (int r = 0; r < 4; ++r)
                        ((float*)Cv)[(size_t)(r0 + r) * 512 + c] =
                            softplusf(acc[i][j][r] + bv);
                } else if (c < 544) {
                    #pragma unroll
                    for (int r = 0; r < 4; ++r)
                        Xv[(size_t)(r0 + r) * 32 + (c - 512)] = acc[i][j][r];
                }
            } else {
                #pragma unroll
                for (int r = 0; r < 4; ++r) {
                    size_t o = (size_t)(r0 + r) * ldc + c;
                    if (EPI == 1) ((ushort*)Cv)[o] = f2b(acc[i][j][r]);
                    else          ((float*)Cv)[o]  = acc[i][j][r];
                }
            }
        }
    }
}

// ---------------------------------------------------------------------------
// Causal depthwise conv (4 taps) + bias + silu, bf16 in/out.
// Vectorized: 4 channels x 8 rows per thread (ushort4 = 8B/lane loads/stores).
// 262144 threads = 1024 blocks; dir = g >> 17.
// ---------------------------------------------------------------------------
__global__ __launch_bounds__(256)
void conv_kernel(const ushort* __restrict__ xz_f, const ushort* __restrict__ xz_b,
                 const float* __restrict__ w_f, const float* __restrict__ w_b,
                 const float* __restrict__ bias_f, const float* __restrict__ bias_b,
                 ushort* __restrict__ xi_f, ushort* __restrict__ xi_b)
{
    int g = blockIdx.x * 256 + threadIdx.x;
    int dir = g >> 17;
    int rem = g & 131071;
    int rb = rem >> 7;        // row group 0..1023
    int cg = rem & 127;       // channel group of 4
    int r0 = rb * 8;
    int d0 = cg * 4;
    int t0 = r0 & (T_SEQ - 1);   // 8 | 4096 -> no batch straddle

    const ushort* xz  = dir ? xz_b : xz_f;
    const float*  w   = dir ? w_b : w_f;
    const float*  bia = dir ? bias_b : bias_f;
    ushort*       xi  = dir ? xi_b : xi_f;

    float wv[4][4], bs[4];
    #pragma unroll
    for (int j = 0; j < 4; ++j) {
        float4 wj = *reinterpret_cast<const float4*>(w + (d0 + j) * 4);
        wv[j][0] = wj.x; wv[j][1] = wj.y; wv[j][2] = wj.z; wv[j][3] = wj.w;
        bs[j] = bia[d0 + j];
    }

    float xv[11][4];
    #pragma unroll
    for (int k = 0; k < 11; ++k) {
        int tt = t0 - 3 + k;
        if (tt >= 0) {
            ushort4 v = *reinterpret_cast<const ushort4*>(
                xz + (size_t)(r0 - 3 + k) * 1024 + d0);
            xv[k][0] = b2f(v.x); xv[k][1] = b2f(v.y);
            xv[k][2] = b2f(v.z); xv[k][3] = b2f(v.w);
        } else {
            xv[k][0] = xv[k][1] = xv[k][2] = xv[k][3] = 0.f;
        }
    }

    #pragma unroll
    for (int t = 0; t < 8; ++t) {
        ushort4 o;
        ushort* op = reinterpret_cast<ushort*>(&o);
        #pragma unroll
        for (int j = 0; j < 4; ++j) {
            float acc = bs[j];
            acc = fmaf(wv[j][0], xv[t + 0][j], acc);
            acc = fmaf(wv[j][1], xv[t + 1][j], acc);
            acc = fmaf(wv[j][2], xv[t + 2][j], acc);
            acc = fmaf(wv[j][3], xv[t + 3][j], acc);
            op[j] = f2b(siluf(acc));
        }
        *reinterpret_cast<ushort4*>(xi + (size_t)(r0 + t) * 512 + d0) = o;
    }
}

// ---------------------------------------------------------------------------
// Chunked scan, packed-fp32 inner loops.  Summaries: Hloc (16/chain) + scalar
// sumdt (Acum recomputed in pass2 as exp(a*sumdt) -- bit-identical).
// ---------------------------------------------------------------------------
__device__ __forceinline__ void scan_head(int bid, int tid,
    int& db, int& b, int& dir, int& chunk, int& d, size_t& row0)
{
    int half = bid & 1;
    int tmp = bid >> 1;
    chunk = tmp & (NCHUNK - 1);
    db = tmp >> 7;
    b = db & 1; dir = db >> 1;
    d = half * 256 + tid;
    row0 = (size_t)b * T_SEQ + (size_t)chunk * CLEN;
}

__device__ __forceinline__ void load_a16(const float* __restrict__ Al, int d,
                                         float* a, bool& fast)
{
    const float4* ap = reinterpret_cast<const float4*>(Al + (size_t)d * 16);
    #pragma unroll
    for (int i = 0; i < 4; ++i) {
        float4 v = ap[i];
        a[4*i+0] = -expf(v.x); a[4*i+1] = -expf(v.y);
        a[4*i+2] = -expf(v.z); a[4*i+3] = -expf(v.w);
    }
    fast = true;
    #pragma unroll
    for (int n = 1; n < 16; ++n)
        fast = fast && (fabsf(a[n] - (float)(n + 1) * a[0]) <= 1e-4f * (float)(n + 1));
}

#define LD16(dst, src_t)                                              \
    {                                                                 \
        const float4* q_ = reinterpret_cast<const float4*>(src_t);    \
        float4 q0 = q_[0], q1 = q_[1], q2 = q_[2], q3 = q_[3];        \
        dst[0]=q0.x; dst[1]=q0.y; dst[2]=q0.z; dst[3]=q0.w;           \
        dst[4]=q1.x; dst[5]=q1.y; dst[6]=q1.z; dst[7]=q1.w;           \
        dst[8]=q2.x; dst[9]=q2.y; dst[10]=q2.z; dst[11]=q2.w;         \
        dst[12]=q3.x; dst[13]=q3.y; dst[14]=q3.z; dst[15]=q3.w;       \
    }

__global__ __launch_bounds__(256)
void scan_pass1(const ushort* __restrict__ xi_f, const ushort* __restrict__ xi_b,
                const float* __restrict__ dt_f, const float* __restrict__ dt_b,
                const float* __restrict__ xd_f, const float* __restrict__ xd_b,
                const float* __restrict__ Al_f, const float* __restrict__ Al_b,
                float* __restrict__ Sdt, float* __restrict__ Hloc)
{
    __shared__ float Bsh[CLEN][16];
    int db, b, dir, chunk, d; size_t row0;
    scan_head(blockIdx.x, threadIdx.x, db, b, dir, chunk, d, row0);

    const ushort* xi = dir ? xi_b : xi_f;
    const float* dt  = dir ? dt_b : dt_f;
    const float* xd  = dir ? xd_b : xd_f;
    const float* Al  = dir ? Al_b : Al_f;

    float a[16]; bool fast;
    load_a16(Al, d, a, fast);

    for (int i = threadIdx.x; i < CLEN * 16; i += 256) {
        int r = i >> 4, n = i & 15;
        Bsh[r][n] = xd[(row0 + r) * 32 + n];
    }
    __syncthreads();

    const ushort* xip = xi + row0 * 512 + d;
    const float*  dtp = dt + row0 * 512 + d;
    float h[16];
    float sumdt = 0.f;

    if (fast) {
        f32x2 h2[8];
        #pragma unroll
        for (int j = 0; j < 8; ++j) h2[j] = (f32x2){0.f, 0.f};
        for (int t = 0; t < CLEN; ++t) {
            float dtv = dtp[(size_t)t * 512];
            float xiv = b2f(xip[(size_t)t * 512]);
            float dbx = dtv * xiv;
            sumdt += dtv;
            float qv = __expf(dtv * a[0]);
            float q2 = qv * qv;
            f32x2 Q2 = (f32x2){q2, q2};
            f32x2 p  = (f32x2){qv, q2};
            f32x2 dbx2 = (f32x2){dbx, dbx};
            const f32x2* bq = reinterpret_cast<const f32x2*>(Bsh[t]);
            #pragma unroll
            for (int j = 0; j < 8; ++j) {
                f32x2 r = bq[j] * dbx2;
                h2[j] = PKFMA(p, h2[j], r);
                if (j < 7) p = p * Q2;
            }
        }
        #pragma unroll
        for (int j = 0; j < 8; ++j) { h[2*j] = h2[j][0]; h[2*j+1] = h2[j][1]; }
    } else {
        #pragma unroll
        for (int n = 0; n < 16; ++n) h[n] = 0.f;
        for (int t = 0; t < CLEN; ++t) {
            float bn[16]; LD16(bn, Bsh[t]);
            float dtv = dtp[(size_t)t * 512];
            float xiv = b2f(xip[(size_t)t * 512]);
            float dbx = dtv * xiv;
            sumdt += dtv;
            #pragma unroll
            for (int n = 0; n < 16; ++n) {
                float dA = __expf(dtv * a[n]);
                h[n] = fmaf(dA, h[n], dbx * bn[n]);
            }
        }
    }

    Sdt[((size_t)db * NCHUNK + chunk) * 512 + d] = sumdt;
    size_t si = ((size_t)((db * NCHUNK + chunk) * 512 + d)) * 16;
    float4* Ho = reinterpret_cast<float4*>(Hloc + si);
    #pragma unroll
    for (int i = 0; i < 4; ++i)
        Ho[i] = make_float4(h[4*i+0], h[4*i+1], h[4*i+2], h[4*i+3]);
}

// pass2: prefix over chunk summaries; Acum recomputed as exp(a*sumdt).
__global__ __launch_bounds__(256)
void scan_pass2(const float* __restrict__ Sdt, const float* __restrict__ Hloc,
                const float* __restrict__ Al_f, const float* __restrict__ Al_b,
                float* __restrict__ Hin)
{
    int tid = blockIdx.x * 256 + threadIdx.x;   // 32768 threads
    int db = tid >> 13;
    int dn = tid & 8191;                        // d*16 + n
    int d = dn >> 4;
    const float* Al = (db >> 1) ? Al_b : Al_f;
    float a = -expf(Al[dn]);

    size_t hbase = (size_t)db * NCHUNK * 8192 + dn;
    size_t sbase = (size_t)db * NCHUNK * 512 + d;
    float h = 0.f;
    #pragma unroll 4
    for (int c = 0; c < NCHUNK; ++c) {
        Hin[hbase + (size_t)c * 8192] = h;
        float dA = __expf(a * Sdt[sbase + (size_t)c * 512]);
        h = fmaf(dA, h, Hloc[hbase + (size_t)c * 8192]);
    }
}

// pass3: replay from h_in, fused gate.  Writes y_all[ROWS][1024]:
//   dir 0 -> cols 0..511 natural rows; dir 1 -> cols 512..1023 unflipped rows.
__global__ __launch_bounds__(256)
void scan_pass3(const ushort* __restrict__ xi_f, const ushort* __restrict__ xi_b,
                const float* __restrict__ dt_f, const float* __restrict__ dt_b,
                const float* __restrict__ xd_f, const float* __restrict__ xd_b,
                const float* __restrict__ Al_f, const float* __restrict__ Al_b,
                const ushort* __restrict__ xz_f, const ushort* __restrict__ xz_b,
                const float* __restrict__ D_f, const float* __restrict__ D_b,
                const float* __restrict__ Hin,
                ushort* __restrict__ y_all)
{
    __shared__ float Bsh[CLEN][16];
    __shared__ float Csh[CLEN][16];
    int db, b, dir, chunk, d; size_t row0;
    scan_head(blockIdx.x, threadIdx.x, db, b, dir, chunk, d, row0);

    const ushort* xi = dir ? xi_b : xi_f;
    const float* dt  = dir ? dt_b : dt_f;
    const float* xd  = dir ? xd_b : xd_f;
    const float* Al  = dir ? Al_b : Al_f;
    const ushort* xz = dir ? xz_b : xz_f;
    const float* Dv  = dir ? D_b  : D_f;

    float a[16]; bool fast;
    load_a16(Al, d, a, fast);
    float Dd = Dv[d];

    for (int i = threadIdx.x; i < CLEN * 32; i += 256) {
        int r = i >> 5, c = i & 31;
        float v = xd[(row0 + r) * 32 + c];
        if (c < 16) Bsh[r][c] = v; else Csh[r][c - 16] = v;
    }
    __syncthreads();

    const ushort* xip = xi + row0 * 512 + d;
    const float*  dtp = dt + row0 * 512 + d;
    const ushort* zp  = xz + row0 * 1024 + 512 + d;

    ushort* yp;
    long ystep;
    if (dir == 0) {
        yp = y_all + row0 * 1024 + d;
        ystep = 1024;
    } else {
        size_t rowu = (size_t)b * T_SEQ + (T_SEQ - 1) - (size_t)chunk * CLEN;
        yp = y_all + rowu * 1024 + 512 + d;
        ystep = -1024;
    }

    size_t si = ((size_t)((db * NCHUNK + chunk) * 512 + d)) * 16;

    if (fast) {
        f32x2 h2[8];
        {
            const f32x2* hp = reinterpret_cast<const f32x2*>(Hin + si);
            #pragma unroll
            for (int j = 0; j < 8; ++j) h2[j] = hp[j];
        }
        for (int t = 0; t < CLEN; ++t) {
            float dtv = dtp[(size_t)t * 512];
            float xiv = b2f(xip[(size_t)t * 512]);
            float zv  = b2f(zp[(size_t)t * 1024]);
            float dbx = dtv * xiv;
            float qv = __expf(dtv * a[0]);
            float q2 = qv * qv;
            f32x2 Q2 = (f32x2){q2, q2};
            f32x2 p  = (f32x2){qv, q2};
            f32x2 dbx2 = (f32x2){dbx, dbx};
            f32x2 yac = (f32x2){0.f, 0.f};
            const f32x2* bq = reinterpret_cast<const f32x2*>(Bsh[t]);
            const f32x2* cq = reinterpret_cast<const f32x2*>(Csh[t]);
            #pragma unroll
            for (int j = 0; j < 8; ++j) {
                f32x2 r = bq[j] * dbx2;
                h2[j] = PKFMA(p, h2[j], r);
                yac = PKFMA(h2[j], cq[j], yac);
                if (j < 7) p = p * Q2;
            }
            float yacc = yac[0] + yac[1];
            yp[(long)t * ystep] = f2b(fmaf(xiv, Dd, yacc) * siluf(zv));
        }
    } else {
        float h[16];
        {
            const float4* hp = reinterpret_cast<const float4*>(Hin + si);
            #pragma unroll
            for (int i = 0; i < 4; ++i) {
                float4 v = hp[i];
                h[4*i+0] = v.x; h[4*i+1] = v.y; h[4*i+2] = v.z; h[4*i+3] = v.w;
            }
        }
        for (int t = 0; t < CLEN; ++t) {
            float bn[16]; LD16(bn, Bsh[t]);
            float cn[16]; LD16(cn, Csh[t]);
            float dtv = dtp[(size_t)t * 512];
            float xiv = b2f(xip[(size_t)t * 512]);
            float zv  = b2f(zp[(size_t)t * 1024]);
            float dbx = dtv * xiv;
            float yacc = 0.f;
            #pragma unroll
            for (int n = 0; n < 16; ++n) {
                float dA = __expf(dtv * a[n]);
                h[n] = fmaf(dA, h[n], dbx * bn[n]);
                yacc = fmaf(h[n], cn[n], yacc);
            }
            yp[(long)t * ystep] = f2b(fmaf(xiv, Dd, yacc) * siluf(zv));
        }
    }
}

// ---------------------------------------------------------------------------
extern "C" void kernel_launch(void* const* d_in, const int* in_sizes, int n_in,
                              void* d_out, int out_size, void* d_ws, size_t ws_size,
                              hipStream_t stream)
{
    const float* x       = (const float*)d_in[0];
    const float* fW_in   = (const float*)d_in[1];
    const float* fconv_w = (const float*)d_in[2];
    const float* fconv_b = (const float*)d_in[3];
    const float* fW_x    = (const float*)d_in[4];
    const float* fW_dt   = (const float*)d_in[5];
    const float* fb_dt   = (const float*)d_in[6];
    const float* fA_log  = (const float*)d_in[7];
    const float* fD      = (const float*)d_in[8];
    const float* fW_out  = (const float*)d_in[9];
    const float* bW_in   = (const float*)d_in[10];
    const float* bconv_w = (const float*)d_in[11];
    const float* bconv_b = (const float*)d_in[12];
    const float* bW_x    = (const float*)d_in[13];
    const float* bW_dt   = (const float*)d_in[14];
    const float* bb_dt   = (const float*)d_in[15];
    const float* bA_log  = (const float*)d_in[16];
    const float* bD      = (const float*)d_in[17];
    const float* bW_out  = (const float*)d_in[18];
    const float* merge   = (const float*)d_in[19];
    float* out = (float*)d_out;

    char* ws = (char*)d_ws;
    ushort* xbh     = (ushort*)ws; ws += (size_t)ROWS * 256 * 2;
    ushort* WinT_f  = (ushort*)ws; ws += (size_t)1024 * 256 * 2;
    ushort* WinT_b  = (ushort*)ws; ws += (size_t)1024 * 256 * 2;
    ushort* WallOut = (ushort*)ws; ws += (size_t)256 * 1024 * 2;
    ushort* Wall_f  = (ushort*)ws; ws += (size_t)640 * 512 * 2;
    ushort* Wall_b  = (ushort*)ws; ws += (size_t)640 * 512 * 2;
    ushort* xz_f    = (ushort*)ws; ws += (size_t)ROWS * 1024 * 2;
    ushort* xz_b    = (ushort*)ws; ws += (size_t)ROWS * 1024 * 2;
    ushort* xi_f    = (ushort*)ws; ws += (size_t)ROWS * 512 * 2;
    ushort* xi_b    = (ushort*)ws; ws += (size_t)ROWS * 512 * 2;
    ushort* y_all   = (ushort*)ws; ws += (size_t)ROWS * 1024 * 2;
    float*  dt_f    = (float*)ws;  ws += (size_t)ROWS * 512 * 4;
    float*  dt_b    = (float*)ws;  ws += (size_t)ROWS * 512 * 4;
    float*  xd_f    = (float*)ws;  ws += (size_t)ROWS * 32 * 4;
    float*  xd_b    = (float*)ws;  ws += (size_t)ROWS * 32 * 4;
    float*  Sdt     = (float*)ws;  ws += (size_t)4 * NCHUNK * 512 * 4;
    float*  Hloc    = (float*)ws;  ws += (size_t)4 * NCHUNK * 8192 * 4;
    float*  Hin     = (float*)ws;  ws += (size_t)4 * NCHUNK * 8192 * 4;

    dim3 blk(256);

    // prep (single launch)
    prep_kernel<<<2624, blk, 0, stream>>>(x, fW_in, bW_in, fW_out, bW_out, merge,
                                          fW_x, fW_dt, bW_x, bW_dt,
                                          xbh, WinT_f, WinT_b, WallOut, Wall_f, Wall_b);

    // G1: xz = x @ W_in, both dirs (z picks dir; bw flips rows)  K=256
    mgemm<64, 128, 1><<<dim3(8, 128, 2), blk, 0, stream>>>(
        xbh, xbh, WinT_f, WinT_b, xz_f, xz_b, nullptr, nullptr, nullptr, nullptr,
        256, 1024, 0, 1, 1, 1);

    // conv + silu (both dirs, vectorized 4ch x 8row)
    conv_kernel<<<1024, blk, 0, stream>>>(xz_f, xz_b, fconv_w, bconv_w,
                                          fconv_b, bconv_b, xi_f, xi_b);

    // dt+xd merged: [dt | xd | pad] = xi @ Wall^T (640 cols = 5x128 tiles)
    mgemm<64, 128, 2><<<dim3(5, 128, 2), blk, 0, stream>>>(
        xi_f, xi_b, Wall_f, Wall_b, dt_f, dt_b, fb_dt, bb_dt, xd_f, xd_b,
        512, 512, 0, 0, 1, 1);

    // chunked scan (packed-fp32; scalar sumdt summaries)
    scan_pass1<<<1024, blk, 0, stream>>>(xi_f, xi_b, dt_f, dt_b, xd_f, xd_b,
                                         fA_log, bA_log, Sdt, Hloc);
    scan_pass2<<<128, blk, 0, stream>>>(Sdt, Hloc, fA_log, bA_log, Hin);
    scan_pass3<<<1024, blk, 0, stream>>>(xi_f, xi_b, dt_f, dt_b, xd_f, xd_b,
                                         fA_log, bA_log, xz_f, xz_b, fD, bD,
                                         Hin, y_all);

    // G5: out = y_all @ WallOut^T  (single un-flipped GEMM, K=1024)
    mgemm<64, 64, 0><<<dim3(4, 128, 1), blk, 0, stream>>>(
        y_all, nullptr, WallOut, nullptr, out, nullptr, nullptr, nullptr,
        nullptr, nullptr, 1024, 256, 0, 0, 0, 1);
}

// Round 12
// 168.360 us; speedup vs baseline: 1.0461x; 1.0461x over previous
//
#include <hip/hip_runtime.h>
#include <math.h>

#define T_SEQ 4096
#define ROWS 8192
#define NCHUNK 128
#define CLEN 32

typedef __attribute__((ext_vector_type(4))) float f32x4;
typedef __attribute__((ext_vector_type(2))) float f32x2;
typedef __attribute__((ext_vector_type(8))) short s16x8;

#if __has_builtin(__builtin_elementwise_fma)
#define PKFMA(a, b, c) __builtin_elementwise_fma((a), (b), (c))
#else
#define PKFMA(a, b, c) ((a) * (b) + (c))
#endif

__device__ __forceinline__ float siluf(float x) { return x / (1.f + __expf(-x)); }
__device__ __forceinline__ float softplusf(float x) {
    return fmaxf(x, 0.f) + __logf(1.f + __expf(-fabsf(x)));
}
__device__ __forceinline__ ushort f2b(float f) {
    uint u = __float_as_uint(f);
    u += 0x7fffu + ((u >> 16) & 1u);
    return (ushort)(u >> 16);
}
__device__ __forceinline__ float b2f(ushort h) { return __uint_as_float(((uint)h) << 16); }

// direct global->LDS, 16B per lane.
__device__ __forceinline__ void gl16(const ushort* g, const char* l)
{
    __builtin_amdgcn_global_load_lds(
        (const __attribute__((address_space(1))) void*)g,
        (__attribute__((address_space(3))) void*)l,
        16, 0, 0);
}

// ---------------------------------------------------------------------------
// Merged prep kernel (one launch):
//  blocks 0..1023    : x fp32 -> bf16 (xbh)
//  1024..1151        : transpose fW_in -> WinT_f [1024][256]
//  1152..1279        : transpose bW_in -> WinT_b
//  1280..1791        : fusewT fw -> WallOut[:, 0:512)
//  1792..2303        : fusewT bw -> WallOut[:, 512:1024)
//  2304..2463        : wallT fw -> Wall_f [640][512]
//  2464..2623        : wallT bw -> Wall_b
// ---------------------------------------------------------------------------
__device__ __forceinline__ void cvt_body(const float* in, ushort* out, int bid, int tid)
{
    int i = bid * 256 + tid;
    const float4* p = reinterpret_cast<const float4*>(in) + (size_t)i * 2;
    float4 a = p[0], b = p[1];
    s16x8 v;
    v[0] = (short)f2b(a.x); v[1] = (short)f2b(a.y); v[2] = (short)f2b(a.z); v[3] = (short)f2b(a.w);
    v[4] = (short)f2b(b.x); v[5] = (short)f2b(b.y); v[6] = (short)f2b(b.z); v[7] = (short)f2b(b.w);
    *reinterpret_cast<s16x8*>(out + (size_t)i * 8) = v;
}

__device__ __forceinline__ void transpose_body(const float* W, ushort* WT,
                                               int Kdim, int Ndim, int bid, int tid)
{
    int idx = bid * 256 + tid;
    int kg8 = Kdim >> 3;
    if (idx >= Ndim * kg8) return;
    int n = idx / kg8, kg = idx - n * kg8;
    s16x8 v;
    #pragma unroll
    for (int i = 0; i < 8; ++i)
        v[i] = (short)f2b(W[(size_t)(kg * 8 + i) * Ndim + n]);
    *reinterpret_cast<s16x8*>(WT + (size_t)n * Kdim + kg * 8) = v;
}

__device__ __forceinline__ void fusew_body(const float* W_out, const float* merge,
                                           ushort* WT, int mrow0, int koff, int bid, int tid)
{
    int idx = bid * 256 + tid;   // dd*256 + j
    int dd = idx >> 8, j = idx & 255;
    float acc = 0.f;
    const float* wr = W_out + dd * 256;
    const float* mc = merge + (size_t)mrow0 * 256 + j;
    #pragma unroll 4
    for (int m = 0; m < 256; ++m)
        acc = fmaf(wr[m], mc[(size_t)m * 256], acc);
    WT[(size_t)j * 1024 + koff + dd] = f2b(acc);
}

__device__ __forceinline__ void wall_body(const float* Wx, const float* Wdt,
                                          ushort* WT, int bid, int tid)
{
    int idx = bid * 256 + tid;   // n*64 + kg
    int n = idx >> 6, kg = idx & 63;
    s16x8 v;
    #pragma unroll
    for (int i = 0; i < 8; ++i) {
        int k = kg * 8 + i;
        float acc = 0.f;
        if (n < 512) {
            #pragma unroll
            for (int j = 0; j < 16; ++j)
                acc = fmaf(Wx[k * 48 + j], Wdt[j * 512 + n], acc);
        } else if (n < 544) {
            acc = Wx[k * 48 + 16 + (n - 512)];
        }
        v[i] = (short)f2b(acc);
    }
    *reinterpret_cast<s16x8*>(WT + (size_t)n * 512 + kg * 8) = v;
}

__global__ __launch_bounds__(256)
void prep_kernel(const float* __restrict__ x,
                 const float* __restrict__ fW_in, const float* __restrict__ bW_in,
                 const float* __restrict__ fW_out, const float* __restrict__ bW_out,
                 const float* __restrict__ merge,
                 const float* __restrict__ fW_x, const float* __restrict__ fW_dt,
                 const float* __restrict__ bW_x, const float* __restrict__ bW_dt,
                 ushort* __restrict__ xbh,
                 ushort* __restrict__ WinT_f, ushort* __restrict__ WinT_b,
                 ushort* __restrict__ WallOut,
                 ushort* __restrict__ Wall_f, ushort* __restrict__ Wall_b)
{
    int bid = blockIdx.x, tid = threadIdx.x;
    if (bid < 1024)        cvt_body(x, xbh, bid, tid);
    else if (bid < 1152)   transpose_body(fW_in, WinT_f, 256, 1024, bid - 1024, tid);
    else if (bid < 1280)   transpose_body(bW_in, WinT_b, 256, 1024, bid - 1152, tid);
    else if (bid < 1792)   fusew_body(fW_out, merge, WallOut, 0, 0, bid - 1280, tid);
    else if (bid < 2304)   fusew_body(bW_out, merge, WallOut, 256, 512, bid - 1792, tid);
    else if (bid < 2464)   wall_body(fW_x, fW_dt, Wall_f, bid - 2304, tid);
    else                   wall_body(bW_x, bW_dt, Wall_b, bid - 2464, tid);
}

// ---------------------------------------------------------------------------
// bf16 MFMA GEMM, m97 structure + bijective XCD swizzle (grid must be %8==0).
// EPI: 0 = f32 store
//      2 = col<512: dt=softplus(acc+bias[c]) -> BF16; col 512..543: xd f32
//      3 = merged-G1: col<1024 -> xz_f[r][c] bf16; col>=1024 ->
//          xz_b[r^4095][c-1024] bf16 (bw computed with natural A rows,
//          written at flipped output rows)
// ---------------------------------------------------------------------------
template<int BM, int BN, int EPI>
__global__ __launch_bounds__(256)
void mgemm(const ushort* __restrict__ A0, const ushort* __restrict__ A1,
           const ushort* __restrict__ B0, const ushort* __restrict__ B1,
           void* __restrict__ C0, void* __restrict__ C1,
           const float* __restrict__ bias0, const float* __restrict__ bias1,
           float* __restrict__ X0, float* __restrict__ X1,
           int K, int ldc, int flip0, int flip1, int zmode, int nseg)
{
    constexpr int MF = BM / 32, NF = BN / 32;
    constexpr int ASTR = BM / 32, BSTR = BN / 32;
    constexpr int ABYTES = BM * 128;
    __shared__ char lds[BM * 128 + BN * 128];

    const int tid = threadIdx.x;
    const int L = tid & 63, w = tid >> 6;
    const int wm = w >> 1, wn = w & 1;

    // bijective XCD swizzle: contiguous logical tiles per XCD (T1)
    const int nbx = gridDim.x, nby = gridDim.y;
    int lin = blockIdx.x + nbx * (blockIdx.y + nby * blockIdx.z);
    int nwg = nbx * nby * gridDim.z;
    int swz = (lin & 7) * (nwg >> 3) + (lin >> 3);
    int bz = swz / (nbx * nby);
    int r2 = swz - bz * nbx * nby;
    int by = r2 / nbx;
    int bx = r2 - by * nbx;

    const int m0 = by * BM, n0 = bx * BN;

    f32x4 acc[MF][NF];
    #pragma unroll
    for (int i = 0; i < MF; ++i)
        #pragma unroll
        for (int j = 0; j < NF; ++j)
            acc[i][j] = (f32x4){0.f, 0.f, 0.f, 0.f};

    const int rsub = L >> 3;
    const int q = (L & 7) ^ rsub;
    const int sb = zmode ? bz : 0;
    const int se = zmode ? sb + 1 : nseg;

    for (int s = sb; s < se; ++s) {
        const ushort* Ap = s ? A1 : A0;
        const ushort* Bp = s ? B1 : B0;
        const int flip = s ? flip1 : flip0;

        const ushort* ap[ASTR];
        const ushort* bp[BSTR];
        #pragma unroll
        for (int c = 0; c < ASTR; ++c) {
            int rg = m0 + (w * ASTR + c) * 8 + rsub;
            if (flip) rg ^= (T_SEQ - 1);
            ap[c] = Ap + (size_t)rg * K + q * 8;
        }
        #pragma unroll
        for (int c = 0; c < BSTR; ++c) {
            int ng = n0 + (w * BSTR + c) * 8 + rsub;
            bp[c] = Bp + (size_t)ng * K + q * 8;
        }

        for (int k0 = 0; k0 < K; k0 += 64) {
            #pragma unroll
            for (int c = 0; c < ASTR; ++c) {
                gl16(ap[c], lds + (w * ASTR + c) * 1024);
                ap[c] += 64;
            }
            #pragma unroll
            for (int c = 0; c < BSTR; ++c) {
                gl16(bp[c], lds + ABYTES + (w * BSTR + c) * 1024);
                bp[c] += 64;
            }
            __syncthreads();
            #pragma unroll
            for (int kk = 0; kk < 2; ++kk) {
                const int sw = (((kk * 4 + (L >> 4)) ^ (L & 7)) << 4);
                s16x8 af[MF], bf[NF];
                #pragma unroll
                for (int i = 0; i < MF; ++i) {
                    int R = wm * (BM / 2) + i * 16 + (L & 15);
                    af[i] = *reinterpret_cast<const s16x8*>(lds + R * 128 + sw);
                }
                #pragma unroll
                for (int j = 0; j < NF; ++j) {
                    int R = wn * (BN / 2) + j * 16 + (L & 15);
                    bf[j] = *reinterpret_cast<const s16x8*>(lds + ABYTES + R * 128 + sw);
                }
                #pragma unroll
                for (int i = 0; i < MF; ++i)
                    #pragma unroll
                    for (int j = 0; j < NF; ++j)
                        acc[i][j] = __builtin_amdgcn_mfma_f32_16x16x32_bf16(
                            af[i], bf[j], acc[i][j], 0, 0, 0);
            }
            __syncthreads();
        }
    }

    void* Cv = (zmode && bz) ? C1 : C0;
    const float* bias = (zmode && bz) ? bias1 : bias0;
    float* Xv = (zmode && bz) ? X1 : X0;
    #pragma unroll
    for (int i = 0; i < MF; ++i) {
        #pragma unroll
        for (int j = 0; j < NF; ++j) {
            int r0 = m0 + wm * (BM / 2) + i * 16 + ((L >> 4) << 2);
            int c  = n0 + wn * (BN / 2) + j * 16 + (L & 15);
            if (EPI == 2) {
                if (c < 512) {
                    float bv = bias[c];
                    #pragma unroll
                    for (int r = 0; r < 4; ++r)
                        ((ushort*)Cv)[(size_t)(r0 + r) * 512 + c] =
                            f2b(softplusf(acc[i][j][r] + bv));
                } else if (c < 544) {
                    #pragma unroll
                    for (int r = 0; r < 4; ++r)
                        Xv[(size_t)(r0 + r) * 32 + (c - 512)] = acc[i][j][r];
                }
            } else if (EPI == 3) {
                if (c < 1024) {
                    #pragma unroll
                    for (int r = 0; r < 4; ++r)
                        ((ushort*)C0)[(size_t)(r0 + r) * 1024 + c] = f2b(acc[i][j][r]);
                } else {
                    #pragma unroll
                    for (int r = 0; r < 4; ++r)
                        ((ushort*)C1)[(size_t)((r0 + r) ^ (T_SEQ - 1)) * 1024 + (c - 1024)] =
                            f2b(acc[i][j][r]);
                }
            } else {
                #pragma unroll
                for (int r = 0; r < 4; ++r)
                    ((float*)Cv)[(size_t)(r0 + r) * ldc + c] = acc[i][j][r];
            }
        }
    }
}

// ---------------------------------------------------------------------------
// Causal depthwise conv (4 taps) + bias + silu, bf16 in/out.
// 4 channels x 8 rows per thread (ushort4 = 8B/lane loads/stores).
// ---------------------------------------------------------------------------
__global__ __launch_bounds__(256)
void conv_kernel(const ushort* __restrict__ xz_f, const ushort* __restrict__ xz_b,
                 const float* __restrict__ w_f, const float* __restrict__ w_b,
                 const float* __restrict__ bias_f, const float* __restrict__ bias_b,
                 ushort* __restrict__ xi_f, ushort* __restrict__ xi_b)
{
    int g = blockIdx.x * 256 + threadIdx.x;
    int dir = g >> 17;
    int rem = g & 131071;
    int rb = rem >> 7;
    int cg = rem & 127;
    int r0 = rb * 8;
    int d0 = cg * 4;
    int t0 = r0 & (T_SEQ - 1);

    const ushort* xz  = dir ? xz_b : xz_f;
    const float*  w   = dir ? w_b : w_f;
    const float*  bia = dir ? bias_b : bias_f;
    ushort*       xi  = dir ? xi_b : xi_f;

    float wv[4][4], bs[4];
    #pragma unroll
    for (int j = 0; j < 4; ++j) {
        float4 wj = *reinterpret_cast<const float4*>(w + (d0 + j) * 4);
        wv[j][0] = wj.x; wv[j][1] = wj.y; wv[j][2] = wj.z; wv[j][3] = wj.w;
        bs[j] = bia[d0 + j];
    }

    float xv[11][4];
    #pragma unroll
    for (int k = 0; k < 11; ++k) {
        int tt = t0 - 3 + k;
        if (tt >= 0) {
            ushort4 v = *reinterpret_cast<const ushort4*>(
                xz + (size_t)(r0 - 3 + k) * 1024 + d0);
            xv[k][0] = b2f(v.x); xv[k][1] = b2f(v.y);
            xv[k][2] = b2f(v.z); xv[k][3] = b2f(v.w);
        } else {
            xv[k][0] = xv[k][1] = xv[k][2] = xv[k][3] = 0.f;
        }
    }

    #pragma unroll
    for (int t = 0; t < 8; ++t) {
        ushort4 o;
        ushort* op = reinterpret_cast<ushort*>(&o);
        #pragma unroll
        for (int j = 0; j < 4; ++j) {
            float acc = bs[j];
            acc = fmaf(wv[j][0], xv[t + 0][j], acc);
            acc = fmaf(wv[j][1], xv[t + 1][j], acc);
            acc = fmaf(wv[j][2], xv[t + 2][j], acc);
            acc = fmaf(wv[j][3], xv[t + 3][j], acc);
            op[j] = f2b(siluf(acc));
        }
        *reinterpret_cast<ushort4*>(xi + (size_t)(r0 + t) * 512 + d0) = o;
    }
}

// ---------------------------------------------------------------------------
// Chunked scan, packed-fp32 inner loops.  dt is BF16.  Summaries: Hloc +
// scalar sumdt (Acum recomputed in pass2 as exp(a*sumdt)).
// ---------------------------------------------------------------------------
__device__ __forceinline__ void scan_head(int bid, int tid,
    int& db, int& b, int& dir, int& chunk, int& d, size_t& row0)
{
    int half = bid & 1;
    int tmp = bid >> 1;
    chunk = tmp & (NCHUNK - 1);
    db = tmp >> 7;
    b = db & 1; dir = db >> 1;
    d = half * 256 + tid;
    row0 = (size_t)b * T_SEQ + (size_t)chunk * CLEN;
}

__device__ __forceinline__ void load_a16(const float* __restrict__ Al, int d,
                                         float* a, bool& fast)
{
    const float4* ap = reinterpret_cast<const float4*>(Al + (size_t)d * 16);
    #pragma unroll
    for (int i = 0; i < 4; ++i) {
        float4 v = ap[i];
        a[4*i+0] = -expf(v.x); a[4*i+1] = -expf(v.y);
        a[4*i+2] = -expf(v.z); a[4*i+3] = -expf(v.w);
    }
    fast = true;
    #pragma unroll
    for (int n = 1; n < 16; ++n)
        fast = fast && (fabsf(a[n] - (float)(n + 1) * a[0]) <= 1e-4f * (float)(n + 1));
}

#define LD16(dst, src_t)                                              \
    {                                                                 \
        const float4* q_ = reinterpret_cast<const float4*>(src_t);    \
        float4 q0 = q_[0], q1 = q_[1], q2 = q_[2], q3 = q_[3];        \
        dst[0]=q0.x; dst[1]=q0.y; dst[2]=q0.z; dst[3]=q0.w;           \
        dst[4]=q1.x; dst[5]=q1.y; dst[6]=q1.z; dst[7]=q1.w;           \
        dst[8]=q2.x; dst[9]=q2.y; dst[10]=q2.z; dst[11]=q2.w;         \
        dst[12]=q3.x; dst[13]=q3.y; dst[14]=q3.z; dst[15]=q3.w;       \
    }

__global__ __launch_bounds__(256)
void scan_pass1(const ushort* __restrict__ xi_f, const ushort* __restrict__ xi_b,
                const ushort* __restrict__ dt_f, const ushort* __restrict__ dt_b,
                const float* __restrict__ xd_f, const float* __restrict__ xd_b,
                const float* __restrict__ Al_f, const float* __restrict__ Al_b,
                float* __restrict__ Sdt, float* __restrict__ Hloc)
{
    __shared__ float Bsh[CLEN][16];
    int db, b, dir, chunk, d; size_t row0;
    scan_head(blockIdx.x, threadIdx.x, db, b, dir, chunk, d, row0);

    const ushort* xi = dir ? xi_b : xi_f;
    const ushort* dt = dir ? dt_b : dt_f;
    const float* xd  = dir ? xd_b : xd_f;
    const float* Al  = dir ? Al_b : Al_f;

    float a[16]; bool fast;
    load_a16(Al, d, a, fast);

    for (int i = threadIdx.x; i < CLEN * 16; i += 256) {
        int r = i >> 4, n = i & 15;
        Bsh[r][n] = xd[(row0 + r) * 32 + n];
    }
    __syncthreads();

    const ushort* xip = xi + row0 * 512 + d;
    const ushort* dtp = dt + row0 * 512 + d;
    float h[16];
    float sumdt = 0.f;

    if (fast) {
        f32x2 h2[8];
        #pragma unroll
        for (int j = 0; j < 8; ++j) h2[j] = (f32x2){0.f, 0.f};
        for (int t = 0; t < CLEN; ++t) {
            float dtv = b2f(dtp[(size_t)t * 512]);
            float xiv = b2f(xip[(size_t)t * 512]);
            float dbx = dtv * xiv;
            sumdt += dtv;
            float qv = __expf(dtv * a[0]);
            float q2 = qv * qv;
            f32x2 Q2 = (f32x2){q2, q2};
            f32x2 p  = (f32x2){qv, q2};
            f32x2 dbx2 = (f32x2){dbx, dbx};
            const f32x2* bq = reinterpret_cast<const f32x2*>(Bsh[t]);
            #pragma unroll
            for (int j = 0; j < 8; ++j) {
                f32x2 r = bq[j] * dbx2;
                h2[j] = PKFMA(p, h2[j], r);
                if (j < 7) p = p * Q2;
            }
        }
        #pragma unroll
        for (int j = 0; j < 8; ++j) { h[2*j] = h2[j][0]; h[2*j+1] = h2[j][1]; }
    } else {
        #pragma unroll
        for (int n = 0; n < 16; ++n) h[n] = 0.f;
        for (int t = 0; t < CLEN; ++t) {
            float bn[16]; LD16(bn, Bsh[t]);
            float dtv = b2f(dtp[(size_t)t * 512]);
            float xiv = b2f(xip[(size_t)t * 512]);
            float dbx = dtv * xiv;
            sumdt += dtv;
            #pragma unroll
            for (int n = 0; n < 16; ++n) {
                float dA = __expf(dtv * a[n]);
                h[n] = fmaf(dA, h[n], dbx * bn[n]);
            }
        }
    }

    Sdt[((size_t)db * NCHUNK + chunk) * 512 + d] = sumdt;
    size_t si = ((size_t)((db * NCHUNK + chunk) * 512 + d)) * 16;
    float4* Ho = reinterpret_cast<float4*>(Hloc + si);
    #pragma unroll
    for (int i = 0; i < 4; ++i)
        Ho[i] = make_float4(h[4*i+0], h[4*i+1], h[4*i+2], h[4*i+3]);
}

// pass2: prefix over chunk summaries; Acum recomputed as exp(a*sumdt).
__global__ __launch_bounds__(256)
void scan_pass2(const float* __restrict__ Sdt, const float* __restrict__ Hloc,
                const float* __restrict__ Al_f, const float* __restrict__ Al_b,
                float* __restrict__ Hin)
{
    int tid = blockIdx.x * 256 + threadIdx.x;   // 32768 threads
    int db = tid >> 13;
    int dn = tid & 8191;
    int d = dn >> 4;
    const float* Al = (db >> 1) ? Al_b : Al_f;
    float a = -expf(Al[dn]);

    size_t hbase = (size_t)db * NCHUNK * 8192 + dn;
    size_t sbase = (size_t)db * NCHUNK * 512 + d;
    float h = 0.f;
    #pragma unroll 4
    for (int c = 0; c < NCHUNK; ++c) {
        Hin[hbase + (size_t)c * 8192] = h;
        float dA = __expf(a * Sdt[sbase + (size_t)c * 512]);
        h = fmaf(dA, h, Hloc[hbase + (size_t)c * 8192]);
    }
}

// pass3: replay from h_in, fused gate.  Writes y_all[ROWS][1024]:
//   dir 0 -> cols 0..511 natural rows; dir 1 -> cols 512..1023 unflipped rows.
__global__ __launch_bounds__(256)
void scan_pass3(const ushort* __restrict__ xi_f, const ushort* __restrict__ xi_b,
                const ushort* __restrict__ dt_f, const ushort* __restrict__ dt_b,
                const float* __restrict__ xd_f, const float* __restrict__ xd_b,
                const float* __restrict__ Al_f, const float* __restrict__ Al_b,
                const ushort* __restrict__ xz_f, const ushort* __restrict__ xz_b,
                const float* __restrict__ D_f, const float* __restrict__ D_b,
                const float* __restrict__ Hin,
                ushort* __restrict__ y_all)
{
    __shared__ float Bsh[CLEN][16];
    __shared__ float Csh[CLEN][16];
    int db, b, dir, chunk, d; size_t row0;
    scan_head(blockIdx.x, threadIdx.x, db, b, dir, chunk, d, row0);

    const ushort* xi = dir ? xi_b : xi_f;
    const ushort* dt = dir ? dt_b : dt_f;
    const float* xd  = dir ? xd_b : xd_f;
    const float* Al  = dir ? Al_b : Al_f;
    const ushort* xz = dir ? xz_b : xz_f;
    const float* Dv  = dir ? D_b  : D_f;

    float a[16]; bool fast;
    load_a16(Al, d, a, fast);
    float Dd = Dv[d];

    for (int i = threadIdx.x; i < CLEN * 32; i += 256) {
        int r = i >> 5, c = i & 31;
        float v = xd[(row0 + r) * 32 + c];
        if (c < 16) Bsh[r][c] = v; else Csh[r][c - 16] = v;
    }
    __syncthreads();

    const ushort* xip = xi + row0 * 512 + d;
    const ushort* dtp = dt + row0 * 512 + d;
    const ushort* zp  = xz + row0 * 1024 + 512 + d;

    ushort* yp;
    long ystep;
    if (dir == 0) {
        yp = y_all + row0 * 1024 + d;
        ystep = 1024;
    } else {
        size_t rowu = (size_t)b * T_SEQ + (T_SEQ - 1) - (size_t)chunk * CLEN;
        yp = y_all + rowu * 1024 + 512 + d;
        ystep = -1024;
    }

    size_t si = ((size_t)((db * NCHUNK + chunk) * 512 + d)) * 16;

    if (fast) {
        f32x2 h2[8];
        {
            const f32x2* hp = reinterpret_cast<const f32x2*>(Hin + si);
            #pragma unroll
            for (int j = 0; j < 8; ++j) h2[j] = hp[j];
        }
        for (int t = 0; t < CLEN; ++t) {
            float dtv = b2f(dtp[(size_t)t * 512]);
            float xiv = b2f(xip[(size_t)t * 512]);
            float zv  = b2f(zp[(size_t)t * 1024]);
            float dbx = dtv * xiv;
            float qv = __expf(dtv * a[0]);
            float q2 = qv * qv;
            f32x2 Q2 = (f32x2){q2, q2};
            f32x2 p  = (f32x2){qv, q2};
            f32x2 dbx2 = (f32x2){dbx, dbx};
            f32x2 yac = (f32x2){0.f, 0.f};
            const f32x2* bq = reinterpret_cast<const f32x2*>(Bsh[t]);
            const f32x2* cq = reinterpret_cast<const f32x2*>(Csh[t]);
            #pragma unroll
            for (int j = 0; j < 8; ++j) {
                f32x2 r = bq[j] * dbx2;
                h2[j] = PKFMA(p, h2[j], r);
                yac = PKFMA(h2[j], cq[j], yac);
                if (j < 7) p = p * Q2;
            }
            float yacc = yac[0] + yac[1];
            yp[(long)t * ystep] = f2b(fmaf(xiv, Dd, yacc) * siluf(zv));
        }
    } else {
        float h[16];
        {
            const float4* hp = reinterpret_cast<const float4*>(Hin + si);
            #pragma unroll
            for (int i = 0; i < 4; ++i) {
                float4 v = hp[i];
                h[4*i+0] = v.x; h[4*i+1] = v.y; h[4*i+2] = v.z; h[4*i+3] = v.w;
            }
        }
        for (int t = 0; t < CLEN; ++t) {
            float bn[16]; LD16(bn, Bsh[t]);
            float cn[16]; LD16(cn, Csh[t]);
            float dtv = b2f(dtp[(size_t)t * 512]);
            float xiv = b2f(xip[(size_t)t * 512]);
            float zv  = b2f(zp[(size_t)t * 1024]);
            float dbx = dtv * xiv;
            float yacc = 0.f;
            #pragma unroll
            for (int n = 0; n < 16; ++n) {
                float dA = __expf(dtv * a[n]);
                h[n] = fmaf(dA, h[n], dbx * bn[n]);
                yacc = fmaf(h[n], cn[n], yacc);
            }
            yp[(long)t * ystep] = f2b(fmaf(xiv, Dd, yacc) * siluf(zv));
        }
    }
}

// ---------------------------------------------------------------------------
extern "C" void kernel_launch(void* const* d_in, const int* in_sizes, int n_in,
                              void* d_out, int out_size, void* d_ws, size_t ws_size,
                              hipStream_t stream)
{
    const float* x       = (const float*)d_in[0];
    const float* fW_in   = (const float*)d_in[1];
    const float* fconv_w = (const float*)d_in[2];
    const float* fconv_b = (const float*)d_in[3];
    const float* fW_x    = (const float*)d_in[4];
    const float* fW_dt   = (const float*)d_in[5];
    const float* fb_dt   = (const float*)d_in[6];
    const float* fA_log  = (const float*)d_in[7];
    const float* fD      = (const float*)d_in[8];
    const float* fW_out  = (const float*)d_in[9];
    const float* bW_in   = (const float*)d_in[10];
    const float* bconv_w = (const float*)d_in[11];
    const float* bconv_b = (const float*)d_in[12];
    const float* bW_x    = (const float*)d_in[13];
    const float* bW_dt   = (const float*)d_in[14];
    const float* bb_dt   = (const float*)d_in[15];
    const float* bA_log  = (const float*)d_in[16];
    const float* bD      = (const float*)d_in[17];
    const float* bW_out  = (const float*)d_in[18];
    const float* merge   = (const float*)d_in[19];
    float* out = (float*)d_out;

    char* ws = (char*)d_ws;
    ushort* xbh     = (ushort*)ws; ws += (size_t)ROWS * 256 * 2;
    ushort* WinT_f  = (ushort*)ws; ws += (size_t)1024 * 256 * 2;
    ushort* WinT_b  = (ushort*)ws; ws += (size_t)1024 * 256 * 2;   // contiguous after WinT_f
    ushort* WallOut = (ushort*)ws; ws += (size_t)256 * 1024 * 2;
    ushort* Wall_f  = (ushort*)ws; ws += (size_t)640 * 512 * 2;
    ushort* Wall_b  = (ushort*)ws; ws += (size_t)640 * 512 * 2;
    ushort* xz_f    = (ushort*)ws; ws += (size_t)ROWS * 1024 * 2;
    ushort* xz_b    = (ushort*)ws; ws += (size_t)ROWS * 1024 * 2;
    ushort* xi_f    = (ushort*)ws; ws += (size_t)ROWS * 512 * 2;
    ushort* xi_b    = (ushort*)ws; ws += (size_t)ROWS * 512 * 2;
    ushort* y_all   = (ushort*)ws; ws += (size_t)ROWS * 1024 * 2;
    ushort* dt_f    = (ushort*)ws; ws += (size_t)ROWS * 512 * 2;
    ushort* dt_b    = (ushort*)ws; ws += (size_t)ROWS * 512 * 2;
    float*  xd_f    = (float*)ws;  ws += (size_t)ROWS * 32 * 4;
    float*  xd_b    = (float*)ws;  ws += (size_t)ROWS * 32 * 4;
    float*  Sdt     = (float*)ws;  ws += (size_t)4 * NCHUNK * 512 * 4;
    float*  Hloc    = (float*)ws;  ws += (size_t)4 * NCHUNK * 8192 * 4;
    float*  Hin     = (float*)ws;  ws += (size_t)4 * NCHUNK * 8192 * 4;

    dim3 blk(256);

    // prep (single launch)
    prep_kernel<<<2624, blk, 0, stream>>>(x, fW_in, bW_in, fW_out, bW_out, merge,
                                          fW_x, fW_dt, bW_x, bW_dt,
                                          xbh, WinT_f, WinT_b, WallOut, Wall_f, Wall_b);

    // G1 merged: [xz_f | xz_b-flipped] = xbh @ [WinT_f;WinT_b]^T  (N=2048, K=256)
    mgemm<64, 128, 3><<<dim3(16, 128), blk, 0, stream>>>(
        xbh, nullptr, WinT_f, nullptr, xz_f, xz_b, nullptr, nullptr, nullptr, nullptr,
        256, 1024, 0, 0, 0, 1);

    // conv + silu (both dirs, vectorized 4ch x 8row)
    conv_kernel<<<1024, blk, 0, stream>>>(xz_f, xz_b, fconv_w, bconv_w,
                                          fconv_b, bconv_b, xi_f, xi_b);

    // dt+xd merged: [dt(bf16) | xd | pad] = xi @ Wall^T (640 cols)
    mgemm<64, 128, 2><<<dim3(5, 128, 2), blk, 0, stream>>>(
        xi_f, xi_b, Wall_f, Wall_b, dt_f, dt_b, fb_dt, bb_dt, xd_f, xd_b,
        512, 512, 0, 0, 1, 1);

    // chunked scan (packed-fp32; bf16 dt; scalar sumdt summaries)
    scan_pass1<<<1024, blk, 0, stream>>>(xi_f, xi_b, dt_f, dt_b, xd_f, xd_b,
                                         fA_log, bA_log, Sdt, Hloc);
    scan_pass2<<<128, blk, 0, stream>>>(Sdt, Hloc, fA_log, bA_log, Hin);
    scan_pass3<<<1024, blk, 0, stream>>>(xi_f, xi_b, dt_f, dt_b, xd_f, xd_b,
                                         fA_log, bA_log, xz_f, xz_b, fD, bD,
                                         Hin, y_all);

    // G5: out = y_all @ WallOut^T  (single un-flipped GEMM, K=1024)
    mgemm<64, 64, 0><<<dim3(4, 128), blk, 0, stream>>>(
        y_all, nullptr, WallOut, nullptr, out, nullptr, nullptr, nullptr,
        nullptr, nullptr, 1024, 256, 0, 0, 0, 1);
}

// Round 13
// 167.222 us; speedup vs baseline: 1.0532x; 1.0068x over previous
//
#include <hip/hip_runtime.h>
#include <math.h>

#define T_SEQ 4096
#define ROWS 8192
#define NCHUNK 128
#define CLEN 32

typedef __attribute__((ext_vector_type(4))) float f32x4;
typedef __attribute__((ext_vector_type(2))) float f32x2;
typedef __attribute__((ext_vector_type(8))) short s16x8;

#if __has_builtin(__builtin_elementwise_fma)
#define PKFMA(a, b, c) __builtin_elementwise_fma((a), (b), (c))
#else
#define PKFMA(a, b, c) ((a) * (b) + (c))
#endif

__device__ __forceinline__ float siluf(float x) { return x / (1.f + __expf(-x)); }
__device__ __forceinline__ float softplusf(float x) {
    return fmaxf(x, 0.f) + __logf(1.f + __expf(-fabsf(x)));
}
__device__ __forceinline__ ushort f2b(float f) {
    uint u = __float_as_uint(f);
    u += 0x7fffu + ((u >> 16) & 1u);
    return (ushort)(u >> 16);
}
__device__ __forceinline__ float b2f(ushort h) { return __uint_as_float(((uint)h) << 16); }

// direct global->LDS, 16B per lane.
__device__ __forceinline__ void gl16(const ushort* g, const char* l)
{
    __builtin_amdgcn_global_load_lds(
        (const __attribute__((address_space(1))) void*)g,
        (__attribute__((address_space(3))) void*)l,
        16, 0, 0);
}

// ---------------------------------------------------------------------------
// Merged prep kernel (one launch) -- unchanged from R12.
// ---------------------------------------------------------------------------
__device__ __forceinline__ void cvt_body(const float* in, ushort* out, int bid, int tid)
{
    int i = bid * 256 + tid;
    const float4* p = reinterpret_cast<const float4*>(in) + (size_t)i * 2;
    float4 a = p[0], b = p[1];
    s16x8 v;
    v[0] = (short)f2b(a.x); v[1] = (short)f2b(a.y); v[2] = (short)f2b(a.z); v[3] = (short)f2b(a.w);
    v[4] = (short)f2b(b.x); v[5] = (short)f2b(b.y); v[6] = (short)f2b(b.z); v[7] = (short)f2b(b.w);
    *reinterpret_cast<s16x8*>(out + (size_t)i * 8) = v;
}

__device__ __forceinline__ void transpose_body(const float* W, ushort* WT,
                                               int Kdim, int Ndim, int bid, int tid)
{
    int idx = bid * 256 + tid;
    int kg8 = Kdim >> 3;
    if (idx >= Ndim * kg8) return;
    int n = idx / kg8, kg = idx - n * kg8;
    s16x8 v;
    #pragma unroll
    for (int i = 0; i < 8; ++i)
        v[i] = (short)f2b(W[(size_t)(kg * 8 + i) * Ndim + n]);
    *reinterpret_cast<s16x8*>(WT + (size_t)n * Kdim + kg * 8) = v;
}

__device__ __forceinline__ void fusew_body(const float* W_out, const float* merge,
                                           ushort* WT, int mrow0, int koff, int bid, int tid)
{
    int idx = bid * 256 + tid;   // dd*256 + j
    int dd = idx >> 8, j = idx & 255;
    float acc = 0.f;
    const float* wr = W_out + dd * 256;
    const float* mc = merge + (size_t)mrow0 * 256 + j;
    #pragma unroll 4
    for (int m = 0; m < 256; ++m)
        acc = fmaf(wr[m], mc[(size_t)m * 256], acc);
    WT[(size_t)j * 1024 + koff + dd] = f2b(acc);
}

__device__ __forceinline__ void wall_body(const float* Wx, const float* Wdt,
                                          ushort* WT, int bid, int tid)
{
    int idx = bid * 256 + tid;   // n*64 + kg
    int n = idx >> 6, kg = idx & 63;
    s16x8 v;
    #pragma unroll
    for (int i = 0; i < 8; ++i) {
        int k = kg * 8 + i;
        float acc = 0.f;
        if (n < 512) {
            #pragma unroll
            for (int j = 0; j < 16; ++j)
                acc = fmaf(Wx[k * 48 + j], Wdt[j * 512 + n], acc);
        } else if (n < 544) {
            acc = Wx[k * 48 + 16 + (n - 512)];
        }
        v[i] = (short)f2b(acc);
    }
    *reinterpret_cast<s16x8*>(WT + (size_t)n * 512 + kg * 8) = v;
}

__global__ __launch_bounds__(256)
void prep_kernel(const float* __restrict__ x,
                 const float* __restrict__ fW_in, const float* __restrict__ bW_in,
                 const float* __restrict__ fW_out, const float* __restrict__ bW_out,
                 const float* __restrict__ merge,
                 const float* __restrict__ fW_x, const float* __restrict__ fW_dt,
                 const float* __restrict__ bW_x, const float* __restrict__ bW_dt,
                 ushort* __restrict__ xbh,
                 ushort* __restrict__ WinT_f, ushort* __restrict__ WinT_b,
                 ushort* __restrict__ WallOut,
                 ushort* __restrict__ Wall_f, ushort* __restrict__ Wall_b)
{
    int bid = blockIdx.x, tid = threadIdx.x;
    if (bid < 1024)        cvt_body(x, xbh, bid, tid);
    else if (bid < 1152)   transpose_body(fW_in, WinT_f, 256, 1024, bid - 1024, tid);
    else if (bid < 1280)   transpose_body(bW_in, WinT_b, 256, 1024, bid - 1152, tid);
    else if (bid < 1792)   fusew_body(fW_out, merge, WallOut, 0, 0, bid - 1280, tid);
    else if (bid < 2304)   fusew_body(bW_out, merge, WallOut, 256, 512, bid - 1792, tid);
    else if (bid < 2464)   wall_body(fW_x, fW_dt, Wall_f, bid - 2304, tid);
    else                   wall_body(bW_x, bW_dt, Wall_b, bid - 2464, tid);
}

// ---------------------------------------------------------------------------
// bf16 MFMA GEMM, m97 structure + XCD swizzle + LDS-transposed coalesced
// epilogue (NEW): C-fragment staged to padded LDS after the K-loop's final
// barrier, then written as ushort8/float4 fully-coalesced rows.
// EPI: 0 = f32 store (transposed)
//      2 = col<512: dt=softplus(acc+bias[c]) -> BF16 (transposed);
//          col 512..543: xd f32 (scalar path, bx==4 blocks only)
//      3 = merged-G1: col<1024 -> xz_f[r][c]; col>=1024 -> xz_b[r^4095][c-1024]
// ---------------------------------------------------------------------------
template<int BM, int BN, int EPI>
__global__ __launch_bounds__(256)
void mgemm(const ushort* __restrict__ A0, const ushort* __restrict__ A1,
           const ushort* __restrict__ B0, const ushort* __restrict__ B1,
           void* __restrict__ C0, void* __restrict__ C1,
           const float* __restrict__ bias0, const float* __restrict__ bias1,
           float* __restrict__ X0, float* __restrict__ X1,
           int K, int ldc, int flip0, int flip1, int zmode, int nseg)
{
    constexpr int MF = BM / 32, NF = BN / 32;
    constexpr int ASTR = BM / 32, BSTR = BN / 32;
    constexpr int ABYTES = BM * 128;
    constexpr int KLDS = BM * 128 + BN * 128;
    constexpr int ELDS = (EPI == 0) ? BM * (BN + 4) * 4 : BM * (BN + 8) * 2;
    constexpr int LDSZ = (KLDS > ELDS) ? KLDS : ELDS;
    __shared__ char lds[LDSZ];

    const int tid = threadIdx.x;
    const int L = tid & 63, w = tid >> 6;
    const int wm = w >> 1, wn = w & 1;

    // bijective XCD swizzle (grid %8==0)
    const int nbx = gridDim.x, nby = gridDim.y;
    int lin = blockIdx.x + nbx * (blockIdx.y + nby * blockIdx.z);
    int nwg = nbx * nby * gridDim.z;
    int swz = (lin & 7) * (nwg >> 3) + (lin >> 3);
    int bz = swz / (nbx * nby);
    int r2 = swz - bz * nbx * nby;
    int by = r2 / nbx;
    int bx = r2 - by * nbx;

    const int m0 = by * BM, n0 = bx * BN;

    f32x4 acc[MF][NF];
    #pragma unroll
    for (int i = 0; i < MF; ++i)
        #pragma unroll
        for (int j = 0; j < NF; ++j)
            acc[i][j] = (f32x4){0.f, 0.f, 0.f, 0.f};

    const int rsub = L >> 3;
    const int q = (L & 7) ^ rsub;
    const int sb = zmode ? bz : 0;
    const int se = zmode ? sb + 1 : nseg;

    for (int s = sb; s < se; ++s) {
        const ushort* Ap = s ? A1 : A0;
        const ushort* Bp = s ? B1 : B0;
        const int flip = s ? flip1 : flip0;

        const ushort* ap[ASTR];
        const ushort* bp[BSTR];
        #pragma unroll
        for (int c = 0; c < ASTR; ++c) {
            int rg = m0 + (w * ASTR + c) * 8 + rsub;
            if (flip) rg ^= (T_SEQ - 1);
            ap[c] = Ap + (size_t)rg * K + q * 8;
        }
        #pragma unroll
        for (int c = 0; c < BSTR; ++c) {
            int ng = n0 + (w * BSTR + c) * 8 + rsub;
            bp[c] = Bp + (size_t)ng * K + q * 8;
        }

        for (int k0 = 0; k0 < K; k0 += 64) {
            #pragma unroll
            for (int c = 0; c < ASTR; ++c) {
                gl16(ap[c], lds + (w * ASTR + c) * 1024);
                ap[c] += 64;
            }
            #pragma unroll
            for (int c = 0; c < BSTR; ++c) {
                gl16(bp[c], lds + ABYTES + (w * BSTR + c) * 1024);
                bp[c] += 64;
            }
            __syncthreads();
            #pragma unroll
            for (int kk = 0; kk < 2; ++kk) {
                const int sw = (((kk * 4 + (L >> 4)) ^ (L & 7)) << 4);
                s16x8 af[MF], bf[NF];
                #pragma unroll
                for (int i = 0; i < MF; ++i) {
                    int R = wm * (BM / 2) + i * 16 + (L & 15);
                    af[i] = *reinterpret_cast<const s16x8*>(lds + R * 128 + sw);
                }
                #pragma unroll
                for (int j = 0; j < NF; ++j) {
                    int R = wn * (BN / 2) + j * 16 + (L & 15);
                    bf[j] = *reinterpret_cast<const s16x8*>(lds + ABYTES + R * 128 + sw);
                }
                #pragma unroll
                for (int i = 0; i < MF; ++i)
                    #pragma unroll
                    for (int j = 0; j < NF; ++j)
                        acc[i][j] = __builtin_amdgcn_mfma_f32_16x16x32_bf16(
                            af[i], bf[j], acc[i][j], 0, 0, 0);
            }
            __syncthreads();
        }
    }

    void* Cv = (zmode && bz) ? C1 : C0;
    const float* bias = (zmode && bz) ? bias1 : bias0;
    float* Xv = (zmode && bz) ? X1 : X0;

    if constexpr (EPI == 3) {
        // stage bf16 tile to padded LDS, then coalesced ushort8 row writes
        ushort* lt = reinterpret_cast<ushort*>(lds);
        #pragma unroll
        for (int i = 0; i < MF; ++i)
            #pragma unroll
            for (int j = 0; j < NF; ++j) {
                int rl = wm * (BM / 2) + i * 16 + ((L >> 4) << 2);
                int cl = wn * (BN / 2) + j * 16 + (L & 15);
                #pragma unroll
                for (int r = 0; r < 4; ++r)
                    lt[(rl + r) * (BN + 8) + cl] = f2b(acc[i][j][r]);
            }
        __syncthreads();
        #pragma unroll
        for (int k = 0; k < BM * BN / 8 / 256; ++k) {
            int id = k * 256 + tid;
            int rl = id / (BN / 8);
            int c8 = (id % (BN / 8)) * 8;
            s16x8 v = *reinterpret_cast<const s16x8*>(lt + rl * (BN + 8) + c8);
            int row = m0 + rl;
            int col = n0 + c8;
            if (col < 1024)
                *reinterpret_cast<s16x8*>((ushort*)C0 + (size_t)row * 1024 + col) = v;
            else
                *reinterpret_cast<s16x8*>((ushort*)C1 +
                    (size_t)(row ^ (T_SEQ - 1)) * 1024 + (col - 1024)) = v;
        }
    } else if constexpr (EPI == 2) {
        if (n0 < 512) {
            ushort* lt = reinterpret_cast<ushort*>(lds);
            #pragma unroll
            for (int i = 0; i < MF; ++i)
                #pragma unroll
                for (int j = 0; j < NF; ++j) {
                    int rl = wm * (BM / 2) + i * 16 + ((L >> 4) << 2);
                    int cl = wn * (BN / 2) + j * 16 + (L & 15);
                    float bv = bias[n0 + cl];
                    #pragma unroll
                    for (int r = 0; r < 4; ++r)
                        lt[(rl + r) * (BN + 8) + cl] = f2b(softplusf(acc[i][j][r] + bv));
                }
            __syncthreads();
            #pragma unroll
            for (int k = 0; k < BM * BN / 8 / 256; ++k) {
                int id = k * 256 + tid;
                int rl = id / (BN / 8);
                int c8 = (id % (BN / 8)) * 8;
                s16x8 v = *reinterpret_cast<const s16x8*>(lt + rl * (BN + 8) + c8);
                *reinterpret_cast<s16x8*>((ushort*)Cv +
                    (size_t)(m0 + rl) * 512 + n0 + c8) = v;
            }
        } else {
            // xd cols 512..543 (f32, scalar)
            #pragma unroll
            for (int i = 0; i < MF; ++i)
                #pragma unroll
                for (int j = 0; j < NF; ++j) {
                    int r0 = m0 + wm * (BM / 2) + i * 16 + ((L >> 4) << 2);
                    int c  = n0 + wn * (BN / 2) + j * 16 + (L & 15);
                    if (c < 544) {
                        #pragma unroll
                        for (int r = 0; r < 4; ++r)
                            Xv[(size_t)(r0 + r) * 32 + (c - 512)] = acc[i][j][r];
                    }
                }
        }
    } else {
        // EPI == 0: f32, transposed via LDS, float4 row writes
        float* lt = reinterpret_cast<float*>(lds);
        #pragma unroll
        for (int i = 0; i < MF; ++i)
            #pragma unroll
            for (int j = 0; j < NF; ++j) {
                int rl = wm * (BM / 2) + i * 16 + ((L >> 4) << 2);
                int cl = wn * (BN / 2) + j * 16 + (L & 15);
                #pragma unroll
                for (int r = 0; r < 4; ++r)
                    lt[(rl + r) * (BN + 4) + cl] = acc[i][j][r];
            }
        __syncthreads();
        #pragma unroll
        for (int k = 0; k < BM * BN / 4 / 256; ++k) {
            int id = k * 256 + tid;
            int rl = id / (BN / 4);
            int c4 = (id % (BN / 4)) * 4;
            float4 v = *reinterpret_cast<const float4*>(lt + rl * (BN + 4) + c4);
            *reinterpret_cast<float4*>((float*)Cv +
                (size_t)(m0 + rl) * ldc + n0 + c4) = v;
        }
    }
}

// ---------------------------------------------------------------------------
// Causal depthwise conv (4 taps) + bias + silu, bf16 in/out.
// 4 channels x 8 rows per thread (ushort4 = 8B/lane loads/stores).
// ---------------------------------------------------------------------------
__global__ __launch_bounds__(256)
void conv_kernel(const ushort* __restrict__ xz_f, const ushort* __restrict__ xz_b,
                 const float* __restrict__ w_f, const float* __restrict__ w_b,
                 const float* __restrict__ bias_f, const float* __restrict__ bias_b,
                 ushort* __restrict__ xi_f, ushort* __restrict__ xi_b)
{
    int g = blockIdx.x * 256 + threadIdx.x;
    int dir = g >> 17;
    int rem = g & 131071;
    int rb = rem >> 7;
    int cg = rem & 127;
    int r0 = rb * 8;
    int d0 = cg * 4;
    int t0 = r0 & (T_SEQ - 1);

    const ushort* xz  = dir ? xz_b : xz_f;
    const float*  w   = dir ? w_b : w_f;
    const float*  bia = dir ? bias_b : bias_f;
    ushort*       xi  = dir ? xi_b : xi_f;

    float wv[4][4], bs[4];
    #pragma unroll
    for (int j = 0; j < 4; ++j) {
        float4 wj = *reinterpret_cast<const float4*>(w + (d0 + j) * 4);
        wv[j][0] = wj.x; wv[j][1] = wj.y; wv[j][2] = wj.z; wv[j][3] = wj.w;
        bs[j] = bia[d0 + j];
    }

    float xv[11][4];
    #pragma unroll
    for (int k = 0; k < 11; ++k) {
        int tt = t0 - 3 + k;
        if (tt >= 0) {
            ushort4 v = *reinterpret_cast<const ushort4*>(
                xz + (size_t)(r0 - 3 + k) * 1024 + d0);
            xv[k][0] = b2f(v.x); xv[k][1] = b2f(v.y);
            xv[k][2] = b2f(v.z); xv[k][3] = b2f(v.w);
        } else {
            xv[k][0] = xv[k][1] = xv[k][2] = xv[k][3] = 0.f;
        }
    }

    #pragma unroll
    for (int t = 0; t < 8; ++t) {
        ushort4 o;
        ushort* op = reinterpret_cast<ushort*>(&o);
        #pragma unroll
        for (int j = 0; j < 4; ++j) {
            float acc = bs[j];
            acc = fmaf(wv[j][0], xv[t + 0][j], acc);
            acc = fmaf(wv[j][1], xv[t + 1][j], acc);
            acc = fmaf(wv[j][2], xv[t + 2][j], acc);
            acc = fmaf(wv[j][3], xv[t + 3][j], acc);
            op[j] = f2b(siluf(acc));
        }
        *reinterpret_cast<ushort4*>(xi + (size_t)(r0 + t) * 512 + d0) = o;
    }
}

// ---------------------------------------------------------------------------
// Chunked scan, packed-fp32 inner loops (unchanged from R12).
// ---------------------------------------------------------------------------
__device__ __forceinline__ void scan_head(int bid, int tid,
    int& db, int& b, int& dir, int& chunk, int& d, size_t& row0)
{
    int half = bid & 1;
    int tmp = bid >> 1;
    chunk = tmp & (NCHUNK - 1);
    db = tmp >> 7;
    b = db & 1; dir = db >> 1;
    d = half * 256 + tid;
    row0 = (size_t)b * T_SEQ + (size_t)chunk * CLEN;
}

__device__ __forceinline__ void load_a16(const float* __restrict__ Al, int d,
                                         float* a, bool& fast)
{
    const float4* ap = reinterpret_cast<const float4*>(Al + (size_t)d * 16);
    #pragma unroll
    for (int i = 0; i < 4; ++i) {
        float4 v = ap[i];
        a[4*i+0] = -expf(v.x); a[4*i+1] = -expf(v.y);
        a[4*i+2] = -expf(v.z); a[4*i+3] = -expf(v.w);
    }
    fast = true;
    #pragma unroll
    for (int n = 1; n < 16; ++n)
        fast = fast && (fabsf(a[n] - (float)(n + 1) * a[0]) <= 1e-4f * (float)(n + 1));
}

#define LD16(dst, src_t)                                              \
    {                                                                 \
        const float4* q_ = reinterpret_cast<const float4*>(src_t);    \
        float4 q0 = q_[0], q1 = q_[1], q2 = q_[2], q3 = q_[3];        \
        dst[0]=q0.x; dst[1]=q0.y; dst[2]=q0.z; dst[3]=q0.w;           \
        dst[4]=q1.x; dst[5]=q1.y; dst[6]=q1.z; dst[7]=q1.w;           \
        dst[8]=q2.x; dst[9]=q2.y; dst[10]=q2.z; dst[11]=q2.w;         \
        dst[12]=q3.x; dst[13]=q3.y; dst[14]=q3.z; dst[15]=q3.w;       \
    }

__global__ __launch_bounds__(256)
void scan_pass1(const ushort* __restrict__ xi_f, const ushort* __restrict__ xi_b,
                const ushort* __restrict__ dt_f, const ushort* __restrict__ dt_b,
                const float* __restrict__ xd_f, const float* __restrict__ xd_b,
                const float* __restrict__ Al_f, const float* __restrict__ Al_b,
                float* __restrict__ Sdt, float* __restrict__ Hloc)
{
    __shared__ float Bsh[CLEN][16];
    int db, b, dir, chunk, d; size_t row0;
    scan_head(blockIdx.x, threadIdx.x, db, b, dir, chunk, d, row0);

    const ushort* xi = dir ? xi_b : xi_f;
    const ushort* dt = dir ? dt_b : dt_f;
    const float* xd  = dir ? xd_b : xd_f;
    const float* Al  = dir ? Al_b : Al_f;

    float a[16]; bool fast;
    load_a16(Al, d, a, fast);

    for (int i = threadIdx.x; i < CLEN * 16; i += 256) {
        int r = i >> 4, n = i & 15;
        Bsh[r][n] = xd[(row0 + r) * 32 + n];
    }
    __syncthreads();

    const ushort* xip = xi + row0 * 512 + d;
    const ushort* dtp = dt + row0 * 512 + d;
    float h[16];
    float sumdt = 0.f;

    if (fast) {
        f32x2 h2[8];
        #pragma unroll
        for (int j = 0; j < 8; ++j) h2[j] = (f32x2){0.f, 0.f};
        for (int t = 0; t < CLEN; ++t) {
            float dtv = b2f(dtp[(size_t)t * 512]);
            float xiv = b2f(xip[(size_t)t * 512]);
            float dbx = dtv * xiv;
            sumdt += dtv;
            float qv = __expf(dtv * a[0]);
            float q2 = qv * qv;
            f32x2 Q2 = (f32x2){q2, q2};
            f32x2 p  = (f32x2){qv, q2};
            f32x2 dbx2 = (f32x2){dbx, dbx};
            const f32x2* bq = reinterpret_cast<const f32x2*>(Bsh[t]);
            #pragma unroll
            for (int j = 0; j < 8; ++j) {
                f32x2 r = bq[j] * dbx2;
                h2[j] = PKFMA(p, h2[j], r);
                if (j < 7) p = p * Q2;
            }
        }
        #pragma unroll
        for (int j = 0; j < 8; ++j) { h[2*j] = h2[j][0]; h[2*j+1] = h2[j][1]; }
    } else {
        #pragma unroll
        for (int n = 0; n < 16; ++n) h[n] = 0.f;
        for (int t = 0; t < CLEN; ++t) {
            float bn[16]; LD16(bn, Bsh[t]);
            float dtv = b2f(dtp[(size_t)t * 512]);
            float xiv = b2f(xip[(size_t)t * 512]);
            float dbx = dtv * xiv;
            sumdt += dtv;
            #pragma unroll
            for (int n = 0; n < 16; ++n) {
                float dA = __expf(dtv * a[n]);
                h[n] = fmaf(dA, h[n], dbx * bn[n]);
            }
        }
    }

    Sdt[((size_t)db * NCHUNK + chunk) * 512 + d] = sumdt;
    size_t si = ((size_t)((db * NCHUNK + chunk) * 512 + d)) * 16;
    float4* Ho = reinterpret_cast<float4*>(Hloc + si);
    #pragma unroll
    for (int i = 0; i < 4; ++i)
        Ho[i] = make_float4(h[4*i+0], h[4*i+1], h[4*i+2], h[4*i+3]);
}

__global__ __launch_bounds__(256)
void scan_pass2(const float* __restrict__ Sdt, const float* __restrict__ Hloc,
                const float* __restrict__ Al_f, const float* __restrict__ Al_b,
                float* __restrict__ Hin)
{
    int tid = blockIdx.x * 256 + threadIdx.x;
    int db = tid >> 13;
    int dn = tid & 8191;
    int d = dn >> 4;
    const float* Al = (db >> 1) ? Al_b : Al_f;
    float a = -expf(Al[dn]);

    size_t hbase = (size_t)db * NCHUNK * 8192 + dn;
    size_t sbase = (size_t)db * NCHUNK * 512 + d;
    float h = 0.f;
    #pragma unroll 4
    for (int c = 0; c < NCHUNK; ++c) {
        Hin[hbase + (size_t)c * 8192] = h;
        float dA = __expf(a * Sdt[sbase + (size_t)c * 512]);
        h = fmaf(dA, h, Hloc[hbase + (size_t)c * 8192]);
    }
}

__global__ __launch_bounds__(256)
void scan_pass3(const ushort* __restrict__ xi_f, const ushort* __restrict__ xi_b,
                const ushort* __restrict__ dt_f, const ushort* __restrict__ dt_b,
                const float* __restrict__ xd_f, const float* __restrict__ xd_b,
                const float* __restrict__ Al_f, const float* __restrict__ Al_b,
                const ushort* __restrict__ xz_f, const ushort* __restrict__ xz_b,
                const float* __restrict__ D_f, const float* __restrict__ D_b,
                const float* __restrict__ Hin,
                ushort* __restrict__ y_all)
{
    __shared__ float Bsh[CLEN][16];
    __shared__ float Csh[CLEN][16];
    int db, b, dir, chunk, d; size_t row0;
    scan_head(blockIdx.x, threadIdx.x, db, b, dir, chunk, d, row0);

    const ushort* xi = dir ? xi_b : xi_f;
    const ushort* dt = dir ? dt_b : dt_f;
    const float* xd  = dir ? xd_b : xd_f;
    const float* Al  = dir ? Al_b : Al_f;
    const ushort* xz = dir ? xz_b : xz_f;
    const float* Dv  = dir ? D_b  : D_f;

    float a[16]; bool fast;
    load_a16(Al, d, a, fast);
    float Dd = Dv[d];

    for (int i = threadIdx.x; i < CLEN * 32; i += 256) {
        int r = i >> 5, c = i & 31;
        float v = xd[(row0 + r) * 32 + c];
        if (c < 16) Bsh[r][c] = v; else Csh[r][c - 16] = v;
    }
    __syncthreads();

    const ushort* xip = xi + row0 * 512 + d;
    const ushort* dtp = dt + row0 * 512 + d;
    const ushort* zp  = xz + row0 * 1024 + 512 + d;

    ushort* yp;
    long ystep;
    if (dir == 0) {
        yp = y_all + row0 * 1024 + d;
        ystep = 1024;
    } else {
        size_t rowu = (size_t)b * T_SEQ + (T_SEQ - 1) - (size_t)chunk * CLEN;
        yp = y_all + rowu * 1024 + 512 + d;
        ystep = -1024;
    }

    size_t si = ((size_t)((db * NCHUNK + chunk) * 512 + d)) * 16;

    if (fast) {
        f32x2 h2[8];
        {
            const f32x2* hp = reinterpret_cast<const f32x2*>(Hin + si);
            #pragma unroll
            for (int j = 0; j < 8; ++j) h2[j] = hp[j];
        }
        for (int t = 0; t < CLEN; ++t) {
            float dtv = b2f(dtp[(size_t)t * 512]);
            float xiv = b2f(xip[(size_t)t * 512]);
            float zv  = b2f(zp[(size_t)t * 1024]);
            float dbx = dtv * xiv;
            float qv = __expf(dtv * a[0]);
            float q2 = qv * qv;
            f32x2 Q2 = (f32x2){q2, q2};
            f32x2 p  = (f32x2){qv, q2};
            f32x2 dbx2 = (f32x2){dbx, dbx};
            f32x2 yac = (f32x2){0.f, 0.f};
            const f32x2* bq = reinterpret_cast<const f32x2*>(Bsh[t]);
            const f32x2* cq = reinterpret_cast<const f32x2*>(Csh[t]);
            #pragma unroll
            for (int j = 0; j < 8; ++j) {
                f32x2 r = bq[j] * dbx2;
                h2[j] = PKFMA(p, h2[j], r);
                yac = PKFMA(h2[j], cq[j], yac);
                if (j < 7) p = p * Q2;
            }
            float yacc = yac[0] + yac[1];
            yp[(long)t * ystep] = f2b(fmaf(xiv, Dd, yacc) * siluf(zv));
        }
    } else {
        float h[16];
        {
            const float4* hp = reinterpret_cast<const float4*>(Hin + si);
            #pragma unroll
            for (int i = 0; i < 4; ++i) {
                float4 v = hp[i];
                h[4*i+0] = v.x; h[4*i+1] = v.y; h[4*i+2] = v.z; h[4*i+3] = v.w;
            }
        }
        for (int t = 0; t < CLEN; ++t) {
            float bn[16]; LD16(bn, Bsh[t]);
            float cn[16]; LD16(cn, Csh[t]);
            float dtv = b2f(dtp[(size_t)t * 512]);
            float xiv = b2f(xip[(size_t)t * 512]);
            float zv  = b2f(zp[(size_t)t * 1024]);
            float dbx = dtv * xiv;
            float yacc = 0.f;
            #pragma unroll
            for (int n = 0; n < 16; ++n) {
                float dA = __expf(dtv * a[n]);
                h[n] = fmaf(dA, h[n], dbx * bn[n]);
                yacc = fmaf(h[n], cn[n], yacc);
            }
            yp[(long)t * ystep] = f2b(fmaf(xiv, Dd, yacc) * siluf(zv));
        }
    }
}

// ---------------------------------------------------------------------------
extern "C" void kernel_launch(void* const* d_in, const int* in_sizes, int n_in,
                              void* d_out, int out_size, void* d_ws, size_t ws_size,
                              hipStream_t stream)
{
    const float* x       = (const float*)d_in[0];
    const float* fW_in   = (const float*)d_in[1];
    const float* fconv_w = (const float*)d_in[2];
    const float* fconv_b = (const float*)d_in[3];
    const float* fW_x    = (const float*)d_in[4];
    const float* fW_dt   = (const float*)d_in[5];
    const float* fb_dt   = (const float*)d_in[6];
    const float* fA_log  = (const float*)d_in[7];
    const float* fD      = (const float*)d_in[8];
    const float* fW_out  = (const float*)d_in[9];
    const float* bW_in   = (const float*)d_in[10];
    const float* bconv_w = (const float*)d_in[11];
    const float* bconv_b = (const float*)d_in[12];
    const float* bW_x    = (const float*)d_in[13];
    const float* bW_dt   = (const float*)d_in[14];
    const float* bb_dt   = (const float*)d_in[15];
    const float* bA_log  = (const float*)d_in[16];
    const float* bD      = (const float*)d_in[17];
    const float* bW_out  = (const float*)d_in[18];
    const float* merge   = (const float*)d_in[19];
    float* out = (float*)d_out;

    char* ws = (char*)d_ws;
    ushort* xbh     = (ushort*)ws; ws += (size_t)ROWS * 256 * 2;
    ushort* WinT_f  = (ushort*)ws; ws += (size_t)1024 * 256 * 2;
    ushort* WinT_b  = (ushort*)ws; ws += (size_t)1024 * 256 * 2;
    ushort* WallOut = (ushort*)ws; ws += (size_t)256 * 1024 * 2;
    ushort* Wall_f  = (ushort*)ws; ws += (size_t)640 * 512 * 2;
    ushort* Wall_b  = (ushort*)ws; ws += (size_t)640 * 512 * 2;
    ushort* xz_f    = (ushort*)ws; ws += (size_t)ROWS * 1024 * 2;
    ushort* xz_b    = (ushort*)ws; ws += (size_t)ROWS * 1024 * 2;
    ushort* xi_f    = (ushort*)ws; ws += (size_t)ROWS * 512 * 2;
    ushort* xi_b    = (ushort*)ws; ws += (size_t)ROWS * 512 * 2;
    ushort* y_all   = (ushort*)ws; ws += (size_t)ROWS * 1024 * 2;
    ushort* dt_f    = (ushort*)ws; ws += (size_t)ROWS * 512 * 2;
    ushort* dt_b    = (ushort*)ws; ws += (size_t)ROWS * 512 * 2;
    float*  xd_f    = (float*)ws;  ws += (size_t)ROWS * 32 * 4;
    float*  xd_b    = (float*)ws;  ws += (size_t)ROWS * 32 * 4;
    float*  Sdt     = (float*)ws;  ws += (size_t)4 * NCHUNK * 512 * 4;
    float*  Hloc    = (float*)ws;  ws += (size_t)4 * NCHUNK * 8192 * 4;
    float*  Hin     = (float*)ws;  ws += (size_t)4 * NCHUNK * 8192 * 4;

    dim3 blk(256);

    // prep (single launch)
    prep_kernel<<<2624, blk, 0, stream>>>(x, fW_in, bW_in, fW_out, bW_out, merge,
                                          fW_x, fW_dt, bW_x, bW_dt,
                                          xbh, WinT_f, WinT_b, WallOut, Wall_f, Wall_b);

    // G1 merged: [xz_f | xz_b-flipped] = xbh @ [WinT_f;WinT_b]^T  (N=2048, K=256)
    mgemm<64, 128, 3><<<dim3(16, 128), blk, 0, stream>>>(
        xbh, nullptr, WinT_f, nullptr, xz_f, xz_b, nullptr, nullptr, nullptr, nullptr,
        256, 1024, 0, 0, 0, 1);

    // conv + silu (both dirs, vectorized 4ch x 8row)
    conv_kernel<<<1024, blk, 0, stream>>>(xz_f, xz_b, fconv_w, bconv_w,
                                          fconv_b, bconv_b, xi_f, xi_b);

    // dt+xd merged: [dt(bf16) | xd | pad] = xi @ Wall^T (640 cols)
    mgemm<64, 128, 2><<<dim3(5, 128, 2), blk, 0, stream>>>(
        xi_f, xi_b, Wall_f, Wall_b, dt_f, dt_b, fb_dt, bb_dt, xd_f, xd_b,
        512, 512, 0, 0, 1, 1);

    // chunked scan (packed-fp32; bf16 dt; scalar sumdt summaries)
    scan_pass1<<<1024, blk, 0, stream>>>(xi_f, xi_b, dt_f, dt_b, xd_f, xd_b,
                                         fA_log, bA_log, Sdt, Hloc);
    scan_pass2<<<128, blk, 0, stream>>>(Sdt, Hloc, fA_log, bA_log, Hin);
    scan_pass3<<<1024, blk, 0, stream>>>(xi_f, xi_b, dt_f, dt_b, xd_f, xd_b,
                                         fA_log, bA_log, xz_f, xz_b, fD, bD,
                                         Hin, y_all);

    // G5: out = y_all @ WallOut^T  (single un-flipped GEMM, K=1024)
    mgemm<64, 64, 0><<<dim3(4, 128), blk, 0, stream>>>(
        y_all, nullptr, WallOut, nullptr, out, nullptr, nullptr, nullptr,
        nullptr, nullptr, 1024, 256, 0, 0, 0, 1);
}

// Round 15
// 167.011 us; speedup vs baseline: 1.0546x; 1.0013x over previous
//
#include <hip/hip_runtime.h>
#include <math.h>

#define T_SEQ 4096
#define ROWS 8192
#define NCHUNK 128
#define CLEN 32

typedef __attribute__((ext_vector_type(4))) float f32x4;
typedef __attribute__((ext_vector_type(2))) float f32x2;
typedef __attribute__((ext_vector_type(8))) short s16x8;

#if __has_builtin(__builtin_elementwise_fma)
#define PKFMA(a, b, c) __builtin_elementwise_fma((a), (b), (c))
#else
#define PKFMA(a, b, c) ((a) * (b) + (c))
#endif

__device__ __forceinline__ float siluf(float x) { return x / (1.f + __expf(-x)); }
__device__ __forceinline__ float softplusf(float x) {
    return fmaxf(x, 0.f) + __logf(1.f + __expf(-fabsf(x)));
}
__device__ __forceinline__ ushort f2b(float f) {
    uint u = __float_as_uint(f);
    u += 0x7fffu + ((u >> 16) & 1u);
    return (ushort)(u >> 16);
}
__device__ __forceinline__ float b2f(ushort h) { return __uint_as_float(((uint)h) << 16); }

// direct global->LDS, 16B per lane.
__device__ __forceinline__ void gl16(const ushort* g, const char* l)
{
    __builtin_amdgcn_global_load_lds(
        (const __attribute__((address_space(1))) void*)g,
        (__attribute__((address_space(3))) void*)l,
        16, 0, 0);
}

// ---------------------------------------------------------------------------
// Merged prep kernel (one launch).
// ---------------------------------------------------------------------------
__device__ __forceinline__ void cvt_body(const float* in, ushort* out, int bid, int tid)
{
    int i = bid * 256 + tid;
    const float4* p = reinterpret_cast<const float4*>(in) + (size_t)i * 2;
    float4 a = p[0], b = p[1];
    s16x8 v;
    v[0] = (short)f2b(a.x); v[1] = (short)f2b(a.y); v[2] = (short)f2b(a.z); v[3] = (short)f2b(a.w);
    v[4] = (short)f2b(b.x); v[5] = (short)f2b(b.y); v[6] = (short)f2b(b.z); v[7] = (short)f2b(b.w);
    *reinterpret_cast<s16x8*>(out + (size_t)i * 8) = v;
}

__device__ __forceinline__ void transpose_body(const float* W, ushort* WT,
                                               int Kdim, int Ndim, int bid, int tid)
{
    int idx = bid * 256 + tid;
    int kg8 = Kdim >> 3;
    if (idx >= Ndim * kg8) return;
    int n = idx / kg8, kg = idx - n * kg8;
    s16x8 v;
    #pragma unroll
    for (int i = 0; i < 8; ++i)
        v[i] = (short)f2b(W[(size_t)(kg * 8 + i) * Ndim + n]);
    *reinterpret_cast<s16x8*>(WT + (size_t)n * Kdim + kg * 8) = v;
}

__device__ __forceinline__ void fusew_body(const float* W_out, const float* merge,
                                           ushort* WT, int mrow0, int koff, int bid, int tid)
{
    int idx = bid * 256 + tid;   // dd*256 + j
    int dd = idx >> 8, j = idx & 255;
    float acc = 0.f;
    const float* wr = W_out + dd * 256;
    const float* mc = merge + (size_t)mrow0 * 256 + j;
    #pragma unroll 4
    for (int m = 0; m < 256; ++m)
        acc = fmaf(wr[m], mc[(size_t)m * 256], acc);
    WT[(size_t)j * 1024 + koff + dd] = f2b(acc);
}

__device__ __forceinline__ void wall_body(const float* Wx, const float* Wdt,
                                          ushort* WT, int bid, int tid)
{
    int idx = bid * 256 + tid;   // n*64 + kg
    int n = idx >> 6, kg = idx & 63;
    s16x8 v;
    #pragma unroll
    for (int i = 0; i < 8; ++i) {
        int k = kg * 8 + i;
        float acc = 0.f;
        if (n < 512) {
            #pragma unroll
            for (int j = 0; j < 16; ++j)
                acc = fmaf(Wx[k * 48 + j], Wdt[j * 512 + n], acc);
        } else if (n < 544) {
            acc = Wx[k * 48 + 16 + (n - 512)];
        }
        v[i] = (short)f2b(acc);
    }
    *reinterpret_cast<s16x8*>(WT + (size_t)n * 512 + kg * 8) = v;
}

__global__ __launch_bounds__(256)
void prep_kernel(const float* __restrict__ x,
                 const float* __restrict__ fW_in, const float* __restrict__ bW_in,
                 const float* __restrict__ fW_out, const float* __restrict__ bW_out,
                 const float* __restrict__ merge,
                 const float* __restrict__ fW_x, const float* __restrict__ fW_dt,
                 const float* __restrict__ bW_x, const float* __restrict__ bW_dt,
                 ushort* __restrict__ xbh,
                 ushort* __restrict__ WinT_f, ushort* __restrict__ WinT_b,
                 ushort* __restrict__ WallOut,
                 ushort* __restrict__ Wall_f, ushort* __restrict__ Wall_b)
{
    int bid = blockIdx.x, tid = threadIdx.x;
    if (bid < 1024)        cvt_body(x, xbh, bid, tid);
    else if (bid < 1152)   transpose_body(fW_in, WinT_f, 256, 1024, bid - 1024, tid);
    else if (bid < 1280)   transpose_body(bW_in, WinT_b, 256, 1024, bid - 1152, tid);
    else if (bid < 1792)   fusew_body(fW_out, merge, WallOut, 0, 0, bid - 1280, tid);
    else if (bid < 2304)   fusew_body(bW_out, merge, WallOut, 256, 512, bid - 1792, tid);
    else if (bid < 2464)   wall_body(fW_x, fW_dt, Wall_f, bid - 2304, tid);
    else                   wall_body(bW_x, bW_dt, Wall_b, bid - 2464, tid);
}

// ---------------------------------------------------------------------------
// bf16 MFMA GEMM, m97 structure + XCD swizzle + LDS-transposed coalesced
// epilogue.
// EPI: 0 = f32 store (transposed)
//      2 = col<512: dt=softplus(acc+bias[c]) -> BF16 (transposed);
//          col 512..543: xd f32 (scalar path, bx==4 blocks only)
//      3 = merged-G1: col<1024 -> xz_f[r][c]; col>=1024 -> xz_b[r^4095][c-1024]
// ---------------------------------------------------------------------------
template<int BM, int BN, int EPI>
__global__ __launch_bounds__(256)
void mgemm(const ushort* __restrict__ A0, const ushort* __restrict__ A1,
           const ushort* __restrict__ B0, const ushort* __restrict__ B1,
           void* __restrict__ C0, void* __restrict__ C1,
           const float* __restrict__ bias0, const float* __restrict__ bias1,
           float* __restrict__ X0, float* __restrict__ X1,
           int K, int ldc, int flip0, int flip1, int zmode, int nseg)
{
    constexpr int MF = BM / 32, NF = BN / 32;
    constexpr int ASTR = BM / 32, BSTR = BN / 32;
    constexpr int ABYTES = BM * 128;
    constexpr int KLDS = BM * 128 + BN * 128;
    constexpr int ELDS = (EPI == 0) ? BM * (BN + 4) * 4 : BM * (BN + 8) * 2;
    constexpr int LDSZ = (KLDS > ELDS) ? KLDS : ELDS;
    __shared__ char lds[LDSZ];

    const int tid = threadIdx.x;
    const int L = tid & 63, w = tid >> 6;
    const int wm = w >> 1, wn = w & 1;

    // bijective XCD swizzle (grid %8==0)
    const int nbx = gridDim.x, nby = gridDim.y;
    int lin = blockIdx.x + nbx * (blockIdx.y + nby * blockIdx.z);
    int nwg = nbx * nby * gridDim.z;
    int swz = (lin & 7) * (nwg >> 3) + (lin >> 3);
    int bz = swz / (nbx * nby);
    int r2 = swz - bz * nbx * nby;
    int by = r2 / nbx;
    int bx = r2 - by * nbx;

    const int m0 = by * BM, n0 = bx * BN;

    f32x4 acc[MF][NF];
    #pragma unroll
    for (int i = 0; i < MF; ++i)
        #pragma unroll
        for (int j = 0; j < NF; ++j)
            acc[i][j] = (f32x4){0.f, 0.f, 0.f, 0.f};

    const int rsub = L >> 3;
    const int q = (L & 7) ^ rsub;
    const int sb = zmode ? bz : 0;
    const int se = zmode ? sb + 1 : nseg;

    for (int s = sb; s < se; ++s) {
        const ushort* Ap = s ? A1 : A0;
        const ushort* Bp = s ? B1 : B0;
        const int flip = s ? flip1 : flip0;

        const ushort* ap[ASTR];
        const ushort* bp[BSTR];
        #pragma unroll
        for (int c = 0; c < ASTR; ++c) {
            int rg = m0 + (w * ASTR + c) * 8 + rsub;
            if (flip) rg ^= (T_SEQ - 1);
            ap[c] = Ap + (size_t)rg * K + q * 8;
        }
        #pragma unroll
        for (int c = 0; c < BSTR; ++c) {
            int ng = n0 + (w * BSTR + c) * 8 + rsub;
            bp[c] = Bp + (size_t)ng * K + q * 8;
        }

        for (int k0 = 0; k0 < K; k0 += 64) {
            #pragma unroll
            for (int c = 0; c < ASTR; ++c) {
                gl16(ap[c], lds + (w * ASTR + c) * 1024);
                ap[c] += 64;
            }
            #pragma unroll
            for (int c = 0; c < BSTR; ++c) {
                gl16(bp[c], lds + ABYTES + (w * BSTR + c) * 1024);
                bp[c] += 64;
            }
            __syncthreads();
            #pragma unroll
            for (int kk = 0; kk < 2; ++kk) {
                const int sw = (((kk * 4 + (L >> 4)) ^ (L & 7)) << 4);
                s16x8 af[MF], bf[NF];
                #pragma unroll
                for (int i = 0; i < MF; ++i) {
                    int R = wm * (BM / 2) + i * 16 + (L & 15);
                    af[i] = *reinterpret_cast<const s16x8*>(lds + R * 128 + sw);
                }
                #pragma unroll
                for (int j = 0; j < NF; ++j) {
                    int R = wn * (BN / 2) + j * 16 + (L & 15);
                    bf[j] = *reinterpret_cast<const s16x8*>(lds + ABYTES + R * 128 + sw);
                }
                #pragma unroll
                for (int i = 0; i < MF; ++i)
                    #pragma unroll
                    for (int j = 0; j < NF; ++j)
                        acc[i][j] = __builtin_amdgcn_mfma_f32_16x16x32_bf16(
                            af[i], bf[j], acc[i][j], 0, 0, 0);
            }
            __syncthreads();
        }
    }

    void* Cv = (zmode && bz) ? C1 : C0;
    const float* bias = (zmode && bz) ? bias1 : bias0;
    float* Xv = (zmode && bz) ? X1 : X0;

    if constexpr (EPI == 3) {
        ushort* lt = reinterpret_cast<ushort*>(lds);
        #pragma unroll
        for (int i = 0; i < MF; ++i)
            #pragma unroll
            for (int j = 0; j < NF; ++j) {
                int rl = wm * (BM / 2) + i * 16 + ((L >> 4) << 2);
                int cl = wn * (BN / 2) + j * 16 + (L & 15);
                #pragma unroll
                for (int r = 0; r < 4; ++r)
                    lt[(rl + r) * (BN + 8) + cl] = f2b(acc[i][j][r]);
            }
        __syncthreads();
        #pragma unroll
        for (int k = 0; k < BM * BN / 8 / 256; ++k) {
            int id = k * 256 + tid;
            int rl = id / (BN / 8);
            int c8 = (id % (BN / 8)) * 8;
            s16x8 v = *reinterpret_cast<const s16x8*>(lt + rl * (BN + 8) + c8);
            int row = m0 + rl;
            int col = n0 + c8;
            if (col < 1024)
                *reinterpret_cast<s16x8*>((ushort*)C0 + (size_t)row * 1024 + col) = v;
            else
                *reinterpret_cast<s16x8*>((ushort*)C1 +
                    (size_t)(row ^ (T_SEQ - 1)) * 1024 + (col - 1024)) = v;
        }
    } else if constexpr (EPI == 2) {
        if (n0 < 512) {
            ushort* lt = reinterpret_cast<ushort*>(lds);
            #pragma unroll
            for (int i = 0; i < MF; ++i)
                #pragma unroll
                for (int j = 0; j < NF; ++j) {
                    int rl = wm * (BM / 2) + i * 16 + ((L >> 4) << 2);
                    int cl = wn * (BN / 2) + j * 16 + (L & 15);
                    float bv = bias[n0 + cl];
                    #pragma unroll
                    for (int r = 0; r < 4; ++r)
                        lt[(rl + r) * (BN + 8) + cl] = f2b(softplusf(acc[i][j][r] + bv));
                }
            __syncthreads();
            #pragma unroll
            for (int k = 0; k < BM * BN / 8 / 256; ++k) {
                int id = k * 256 + tid;
                int rl = id / (BN / 8);
                int c8 = (id % (BN / 8)) * 8;
                s16x8 v = *reinterpret_cast<const s16x8*>(lt + rl * (BN + 8) + c8);
                *reinterpret_cast<s16x8*>((ushort*)Cv +
                    (size_t)(m0 + rl) * 512 + n0 + c8) = v;
            }
        } else {
            #pragma unroll
            for (int i = 0; i < MF; ++i)
                #pragma unroll
                for (int j = 0; j < NF; ++j) {
                    int r0 = m0 + wm * (BM / 2) + i * 16 + ((L >> 4) << 2);
                    int c  = n0 + wn * (BN / 2) + j * 16 + (L & 15);
                    if (c < 544) {
                        #pragma unroll
                        for (int r = 0; r < 4; ++r)
                            Xv[(size_t)(r0 + r) * 32 + (c - 512)] = acc[i][j][r];
                    }
                }
        }
    } else {
        float* lt = reinterpret_cast<float*>(lds);
        #pragma unroll
        for (int i = 0; i < MF; ++i)
            #pragma unroll
            for (int j = 0; j < NF; ++j) {
                int rl = wm * (BM / 2) + i * 16 + ((L >> 4) << 2);
                int cl = wn * (BN / 2) + j * 16 + (L & 15);
                #pragma unroll
                for (int r = 0; r < 4; ++r)
                    lt[(rl + r) * (BN + 4) + cl] = acc[i][j][r];
            }
        __syncthreads();
        #pragma unroll
        for (int k = 0; k < BM * BN / 4 / 256; ++k) {
            int id = k * 256 + tid;
            int rl = id / (BN / 4);
            int c4 = (id % (BN / 4)) * 4;
            float4 v = *reinterpret_cast<const float4*>(lt + rl * (BN + 4) + c4);
            *reinterpret_cast<float4*>((float*)Cv +
                (size_t)(m0 + rl) * ldc + n0 + c4) = v;
        }
    }
}

// ---------------------------------------------------------------------------
// Causal depthwise conv (4 taps) + bias + silu, bf16 in/out.
// 4 channels x 8 rows per thread (ushort4 = 8B/lane loads/stores).
// ---------------------------------------------------------------------------
__global__ __launch_bounds__(256)
void conv_kernel(const ushort* __restrict__ xz_f, const ushort* __restrict__ xz_b,
                 const float* __restrict__ w_f, const float* __restrict__ w_b,
                 const float* __restrict__ bias_f, const float* __restrict__ bias_b,
                 ushort* __restrict__ xi_f, ushort* __restrict__ xi_b)
{
    int g = blockIdx.x * 256 + threadIdx.x;
    int dir = g >> 17;
    int rem = g & 131071;
    int rb = rem >> 7;
    int cg = rem & 127;
    int r0 = rb * 8;
    int d0 = cg * 4;
    int t0 = r0 & (T_SEQ - 1);

    const ushort* xz  = dir ? xz_b : xz_f;
    const float*  w   = dir ? w_b : w_f;
    const float*  bia = dir ? bias_b : bias_f;
    ushort*       xi  = dir ? xi_b : xi_f;

    float wv[4][4], bs[4];
    #pragma unroll
    for (int j = 0; j < 4; ++j) {
        float4 wj = *reinterpret_cast<const float4*>(w + (d0 + j) * 4);
        wv[j][0] = wj.x; wv[j][1] = wj.y; wv[j][2] = wj.z; wv[j][3] = wj.w;
        bs[j] = bia[d0 + j];
    }

    float xv[11][4];
    #pragma unroll
    for (int k = 0; k < 11; ++k) {
        int tt = t0 - 3 + k;
        if (tt >= 0) {
            ushort4 v = *reinterpret_cast<const ushort4*>(
                xz + (size_t)(r0 - 3 + k) * 1024 + d0);
            xv[k][0] = b2f(v.x); xv[k][1] = b2f(v.y);
            xv[k][2] = b2f(v.z); xv[k][3] = b2f(v.w);
        } else {
            xv[k][0] = xv[k][1] = xv[k][2] = xv[k][3] = 0.f;
        }
    }

    #pragma unroll
    for (int t = 0; t < 8; ++t) {
        ushort4 o;
        ushort* op = reinterpret_cast<ushort*>(&o);
        #pragma unroll
        for (int j = 0; j < 4; ++j) {
            float acc = bs[j];
            acc = fmaf(wv[j][0], xv[t + 0][j], acc);
            acc = fmaf(wv[j][1], xv[t + 1][j], acc);
            acc = fmaf(wv[j][2], xv[t + 2][j], acc);
            acc = fmaf(wv[j][3], xv[t + 3][j], acc);
            op[j] = f2b(siluf(acc));
        }
        *reinterpret_cast<ushort4*>(xi + (size_t)(r0 + t) * 512 + d0) = o;
    }
}

// ---------------------------------------------------------------------------
// Chunked scan, packed-fp32 inner loops.  dt is BF16.  Summaries: Hloc +
// scalar sumdt (Acum recomputed in pass2 as exp(a*sumdt)).
// ---------------------------------------------------------------------------
__device__ __forceinline__ void scan_head(int bid, int tid,
    int& db, int& b, int& dir, int& chunk, int& d, size_t& row0)
{
    int half = bid & 1;
    int tmp = bid >> 1;
    chunk = tmp & (NCHUNK - 1);
    db = tmp >> 7;
    b = db & 1; dir = db >> 1;
    d = half * 256 + tid;
    row0 = (size_t)b * T_SEQ + (size_t)chunk * CLEN;
}

__device__ __forceinline__ void load_a16(const float* __restrict__ Al, int d,
                                         float* a, bool& fast)
{
    const float4* ap = reinterpret_cast<const float4*>(Al + (size_t)d * 16);
    #pragma unroll
    for (int i = 0; i < 4; ++i) {
        float4 v = ap[i];
        a[4*i+0] = -expf(v.x); a[4*i+1] = -expf(v.y);
        a[4*i+2] = -expf(v.z); a[4*i+3] = -expf(v.w);
    }
    fast = true;
    #pragma unroll
    for (int n = 1; n < 16; ++n)
        fast = fast && (fabsf(a[n] - (float)(n + 1) * a[0]) <= 1e-4f * (float)(n + 1));
}

#define LD16(dst, src_t)                                              \
    {                                                                 \
        const float4* q_ = reinterpret_cast<const float4*>(src_t);    \
        float4 q0 = q_[0], q1 = q_[1], q2 = q_[2], q3 = q_[3];        \
        dst[0]=q0.x; dst[1]=q0.y; dst[2]=q0.z; dst[3]=q0.w;           \
        dst[4]=q1.x; dst[5]=q1.y; dst[6]=q1.z; dst[7]=q1.w;           \
        dst[8]=q2.x; dst[9]=q2.y; dst[10]=q2.z; dst[11]=q2.w;         \
        dst[12]=q3.x; dst[13]=q3.y; dst[14]=q3.z; dst[15]=q3.w;       \
    }

__global__ __launch_bounds__(256)
void scan_pass1(const ushort* __restrict__ xi_f, const ushort* __restrict__ xi_b,
                const ushort* __restrict__ dt_f, const ushort* __restrict__ dt_b,
                const float* __restrict__ xd_f, const float* __restrict__ xd_b,
                const float* __restrict__ Al_f, const float* __restrict__ Al_b,
                float* __restrict__ Sdt, float* __restrict__ Hloc)
{
    __shared__ float Bsh[CLEN][16];
    int db, b, dir, chunk, d; size_t row0;
    scan_head(blockIdx.x, threadIdx.x, db, b, dir, chunk, d, row0);

    const ushort* xi = dir ? xi_b : xi_f;
    const ushort* dt = dir ? dt_b : dt_f;
    const float* xd  = dir ? xd_b : xd_f;
    const float* Al  = dir ? Al_b : Al_f;

    float a[16]; bool fast;
    load_a16(Al, d, a, fast);

    for (int i = threadIdx.x; i < CLEN * 16; i += 256) {
        int r = i >> 4, n = i & 15;
        Bsh[r][n] = xd[(row0 + r) * 32 + n];
    }
    __syncthreads();

    const ushort* xip = xi + row0 * 512 + d;
    const ushort* dtp = dt + row0 * 512 + d;
    float h[16];
    float sumdt = 0.f;

    if (fast) {
        f32x2 h2[8];
        #pragma unroll
        for (int j = 0; j < 8; ++j) h2[j] = (f32x2){0.f, 0.f};
        for (int t = 0; t < CLEN; ++t) {
            float dtv = b2f(dtp[(size_t)t * 512]);
            float xiv = b2f(xip[(size_t)t * 512]);
            float dbx = dtv * xiv;
            sumdt += dtv;
            float qv = __expf(dtv * a[0]);
            float q2 = qv * qv;
            f32x2 Q2 = (f32x2){q2, q2};
            f32x2 p  = (f32x2){qv, q2};
            f32x2 dbx2 = (f32x2){dbx, dbx};
            const f32x2* bq = reinterpret_cast<const f32x2*>(Bsh[t]);
            #pragma unroll
            for (int j = 0; j < 8; ++j) {
                f32x2 r = bq[j] * dbx2;
                h2[j] = PKFMA(p, h2[j], r);
                if (j < 7) p = p * Q2;
            }
        }
        #pragma unroll
        for (int j = 0; j < 8; ++j) { h[2*j] = h2[j][0]; h[2*j+1] = h2[j][1]; }
    } else {
        #pragma unroll
        for (int n = 0; n < 16; ++n) h[n] = 0.f;
        for (int t = 0; t < CLEN; ++t) {
            float bn[16]; LD16(bn, Bsh[t]);
            float dtv = b2f(dtp[(size_t)t * 512]);
            float xiv = b2f(xip[(size_t)t * 512]);
            float dbx = dtv * xiv;
            sumdt += dtv;
            #pragma unroll
            for (int n = 0; n < 16; ++n) {
                float dA = __expf(dtv * a[n]);
                h[n] = fmaf(dA, h[n], dbx * bn[n]);
            }
        }
    }

    Sdt[((size_t)db * NCHUNK + chunk) * 512 + d] = sumdt;
    size_t si = ((size_t)((db * NCHUNK + chunk) * 512 + d)) * 16;
    float4* Ho = reinterpret_cast<float4*>(Hloc + si);
    #pragma unroll
    for (int i = 0; i < 4; ++i)
        Ho[i] = make_float4(h[4*i+0], h[4*i+1], h[4*i+2], h[4*i+3]);
}

__global__ __launch_bounds__(256)
void scan_pass2(const float* __restrict__ Sdt, const float* __restrict__ Hloc,
                const float* __restrict__ Al_f, const float* __restrict__ Al_b,
                float* __restrict__ Hin)
{
    int tid = blockIdx.x * 256 + threadIdx.x;
    int db = tid >> 13;
    int dn = tid & 8191;
    int d = dn >> 4;
    const float* Al = (db >> 1) ? Al_b : Al_f;
    float a = -expf(Al[dn]);

    size_t hbase = (size_t)db * NCHUNK * 8192 + dn;
    size_t sbase = (size_t)db * NCHUNK * 512 + d;
    float h = 0.f;
    #pragma unroll 4
    for (int c = 0; c < NCHUNK; ++c) {
        Hin[hbase + (size_t)c * 8192] = h;
        float dA = __expf(a * Sdt[sbase + (size_t)c * 512]);
        h = fmaf(dA, h, Hloc[hbase + (size_t)c * 8192]);
    }
}

__global__ __launch_bounds__(256)
void scan_pass3(const ushort* __restrict__ xi_f, const ushort* __restrict__ xi_b,
                const ushort* __restrict__ dt_f, const ushort* __restrict__ dt_b,
                const float* __restrict__ xd_f, const float* __restrict__ xd_b,
                const float* __restrict__ Al_f, const float* __restrict__ Al_b,
                const ushort* __restrict__ xz_f, const ushort* __restrict__ xz_b,
                const float* __restrict__ D_f, const float* __restrict__ D_b,
                const float* __restrict__ Hin,
                ushort* __restrict__ y_all)
{
    __shared__ float Bsh[CLEN][16];
    __shared__ float Csh[CLEN][16];
    int db, b, dir, chunk, d; size_t row0;
    scan_head(blockIdx.x, threadIdx.x, db, b, dir, chunk, d, row0);

    const ushort* xi = dir ? xi_b : xi_f;
    const ushort* dt = dir ? dt_b : dt_f;
    const float* xd  = dir ? xd_b : xd_f;
    const float* Al  = dir ? Al_b : Al_f;
    const ushort* xz = dir ? xz_b : xz_f;
    const float* Dv  = dir ? D_b  : D_f;

    float a[16]; bool fast;
    load_a16(Al, d, a, fast);
    float Dd = Dv[d];

    for (int i = threadIdx.x; i < CLEN * 32; i += 256) {
        int r = i >> 5, c = i & 31;
        float v = xd[(row0 + r) * 32 + c];
        if (c < 16) Bsh[r][c] = v; else Csh[r][c - 16] = v;
    }
    __syncthreads();

    const ushort* xip = xi + row0 * 512 + d;
    const ushort* dtp = dt + row0 * 512 + d;
    const ushort* zp  = xz + row0 * 1024 + 512 + d;

    ushort* yp;
    long ystep;
    if (dir == 0) {
        yp = y_all + row0 * 1024 + d;
        ystep = 1024;
    } else {
        size_t rowu = (size_t)b * T_SEQ + (T_SEQ - 1) - (size_t)chunk * CLEN;
        yp = y_all + rowu * 1024 + 512 + d;
        ystep = -1024;
    }

    size_t si = ((size_t)((db * NCHUNK + chunk) * 512 + d)) * 16;

    if (fast) {
        f32x2 h2[8];
        {
            const f32x2* hp = reinterpret_cast<const f32x2*>(Hin + si);
            #pragma unroll
            for (int j = 0; j < 8; ++j) h2[j] = hp[j];
        }
        for (int t = 0; t < CLEN; ++t) {
            float dtv = b2f(dtp[(size_t)t * 512]);
            float xiv = b2f(xip[(size_t)t * 512]);
            float zv  = b2f(zp[(size_t)t * 1024]);
            float dbx = dtv * xiv;
            float qv = __expf(dtv * a[0]);
            float q2 = qv * qv;
            f32x2 Q2 = (f32x2){q2, q2};
            f32x2 p  = (f32x2){qv, q2};
            f32x2 dbx2 = (f32x2){dbx, dbx};
            f32x2 yac = (f32x2){0.f, 0.f};
            const f32x2* bq = reinterpret_cast<const f32x2*>(Bsh[t]);
            const f32x2* cq = reinterpret_cast<const f32x2*>(Csh[t]);
            #pragma unroll
            for (int j = 0; j < 8; ++j) {
                f32x2 r = bq[j] * dbx2;
                h2[j] = PKFMA(p, h2[j], r);
                yac = PKFMA(h2[j], cq[j], yac);
                if (j < 7) p = p * Q2;
            }
            float yacc = yac[0] + yac[1];
            yp[(long)t * ystep] = f2b(fmaf(xiv, Dd, yacc) * siluf(zv));
        }
    } else {
        float h[16];
        {
            const float4* hp = reinterpret_cast<const float4*>(Hin + si);
            #pragma unroll
            for (int i = 0; i < 4; ++i) {
                float4 v = hp[i];
                h[4*i+0] = v.x; h[4*i+1] = v.y; h[4*i+2] = v.z; h[4*i+3] = v.w;
            }
        }
        for (int t = 0; t < CLEN; ++t) {
            float bn[16]; LD16(bn, Bsh[t]);
            float cn[16]; LD16(cn, Csh[t]);
            float dtv = b2f(dtp[(size_t)t * 512]);
            float xiv = b2f(xip[(size_t)t * 512]);
            float zv  = b2f(zp[(size_t)t * 1024]);
            float dbx = dtv * xiv;
            float yacc = 0.f;
            #pragma unroll
            for (int n = 0; n < 16; ++n) {
                float dA = __expf(dtv * a[n]);
                h[n] = fmaf(dA, h[n], dbx * bn[n]);
                yacc = fmaf(h[n], cn[n], yacc);
            }
            yp[(long)t * ystep] = f2b(fmaf(xiv, Dd, yacc) * siluf(zv));
        }
    }
}

// ---------------------------------------------------------------------------
extern "C" void kernel_launch(void* const* d_in, const int* in_sizes, int n_in,
                              void* d_out, int out_size, void* d_ws, size_t ws_size,
                              hipStream_t stream)
{
    const float* x       = (const float*)d_in[0];
    const float* fW_in   = (const float*)d_in[1];
    const float* fconv_w = (const float*)d_in[2];
    const float* fconv_b = (const float*)d_in[3];
    const float* fW_x    = (const float*)d_in[4];
    const float* fW_dt   = (const float*)d_in[5];
    const float* fb_dt   = (const float*)d_in[6];
    const float* fA_log  = (const float*)d_in[7];
    const float* fD      = (const float*)d_in[8];
    const float* fW_out  = (const float*)d_in[9];
    const float* bW_in   = (const float*)d_in[10];
    const float* bconv_w = (const float*)d_in[11];
    const float* bconv_b = (const float*)d_in[12];
    const float* bW_x    = (const float*)d_in[13];
    const float* bW_dt   = (const float*)d_in[14];
    const float* bb_dt   = (const float*)d_in[15];
    const float* bA_log  = (const float*)d_in[16];
    const float* bD      = (const float*)d_in[17];
    const float* bW_out  = (const float*)d_in[18];
    const float* merge   = (const float*)d_in[19];
    float* out = (float*)d_out;

    char* ws = (char*)d_ws;
    ushort* xbh     = (ushort*)ws; ws += (size_t)ROWS * 256 * 2;
    ushort* WinT_f  = (ushort*)ws; ws += (size_t)1024 * 256 * 2;
    ushort* WinT_b  = (ushort*)ws; ws += (size_t)1024 * 256 * 2;
    ushort* WallOut = (ushort*)ws; ws += (size_t)256 * 1024 * 2;
    ushort* Wall_f  = (ushort*)ws; ws += (size_t)640 * 512 * 2;
    ushort* Wall_b  = (ushort*)ws; ws += (size_t)640 * 512 * 2;
    ushort* xz_f    = (ushort*)ws; ws += (size_t)ROWS * 1024 * 2;
    ushort* xz_b    = (ushort*)ws; ws += (size_t)ROWS * 1024 * 2;
    ushort* xi_f    = (ushort*)ws; ws += (size_t)ROWS * 512 * 2;
    ushort* xi_b    = (ushort*)ws; ws += (size_t)ROWS * 512 * 2;
    ushort* y_all   = (ushort*)ws; ws += (size_t)ROWS * 1024 * 2;
    ushort* dt_f    = (ushort*)ws; ws += (size_t)ROWS * 512 * 2;
    ushort* dt_b    = (ushort*)ws; ws += (size_t)ROWS * 512 * 2;
    float*  xd_f    = (float*)ws;  ws += (size_t)ROWS * 32 * 4;
    float*  xd_b    = (float*)ws;  ws += (size_t)ROWS * 32 * 4;
    float*  Sdt     = (float*)ws;  ws += (size_t)4 * NCHUNK * 512 * 4;
    float*  Hloc    = (float*)ws;  ws += (size_t)4 * NCHUNK * 8192 * 4;
    float*  Hin     = (float*)ws;  ws += (size_t)4 * NCHUNK * 8192 * 4;

    dim3 blk(256);

    // prep (single launch)
    prep_kernel<<<2624, blk, 0, stream>>>(x, fW_in, bW_in, fW_out, bW_out, merge,
                                          fW_x, fW_dt, bW_x, bW_dt,
                                          xbh, WinT_f, WinT_b, WallOut, Wall_f, Wall_b);

    // G1 merged: [xz_f | xz_b-flipped] = xbh @ [WinT_f;WinT_b]^T  (N=2048, K=256)
    mgemm<64, 128, 3><<<dim3(16, 128), blk, 0, stream>>>(
        xbh, nullptr, WinT_f, nullptr, xz_f, xz_b, nullptr, nullptr, nullptr, nullptr,
        256, 1024, 0, 0, 0, 1);

    // conv + silu (both dirs, vectorized 4ch x 8row)
    conv_kernel<<<1024, blk, 0, stream>>>(xz_f, xz_b, fconv_w, bconv_w,
                                          fconv_b, bconv_b, xi_f, xi_b);

    // dt+xd merged: [dt(bf16) | xd | pad] = xi @ Wall^T (640 cols)
    mgemm<64, 128, 2><<<dim3(5, 128, 2), blk, 0, stream>>>(
        xi_f, xi_b, Wall_f, Wall_b, dt_f, dt_b, fb_dt, bb_dt, xd_f, xd_b,
        512, 512, 0, 0, 1, 1);

    // chunked scan (packed-fp32; bf16 dt; scalar sumdt summaries)
    scan_pass1<<<1024, blk, 0, stream>>>(xi_f, xi_b, dt_f, dt_b, xd_f, xd_b,
                                         fA_log, bA_log, Sdt, Hloc);
    scan_pass2<<<128, blk, 0, stream>>>(Sdt, Hloc, fA_log, bA_log, Hin);
    scan_pass3<<<1024, blk, 0, stream>>>(xi_f, xi_b, dt_f, dt_b, xd_f, xd_b,
                                         fA_log, bA_log, xz_f, xz_b, fD, bD,
                                         Hin, y_all);

    // G5: out = y_all @ WallOut^T  (single un-flipped GEMM, K=1024)
    mgemm<64, 64, 0><<<dim3(4, 128), blk, 0, stream>>>(
        y_all, nullptr, WallOut, nullptr, out, nullptr, nullptr, nullptr,
        nullptr, nullptr, 1024, 256, 0, 0, 0, 1);
}